// Round 1
// baseline (507.565 us; speedup 1.0000x reference)
//
#include <hip/hip_runtime.h>
#include <math.h>

#define FEAT 128

// ---------------------------------------------------------------------------
// Kernel A: init — zero the accumulator (d_out), deg=1.0 (self-loop), BN sums=0
// ---------------------------------------------------------------------------
__global__ __launch_bounds__(256) void k_init(float* __restrict__ out, float* __restrict__ deg,
                                              float* __restrict__ bnsum, float* __restrict__ bnsq,
                                              int total, int n) {
    int i = blockIdx.x * 256 + threadIdx.x;
    if (i < total) out[i] = 0.0f;
    if (i < n) deg[i] = 1.0f;
    if (i < FEAT) { bnsum[i] = 0.0f; bnsq[i] = 0.0f; }
}

// ---------------------------------------------------------------------------
// Kernel B: degree accumulation over edge targets (col)
// ---------------------------------------------------------------------------
__global__ __launch_bounds__(256) void k_deg(const int* __restrict__ ei, const float* __restrict__ ew,
                                             float* __restrict__ deg, int E) {
    int e = blockIdx.x * 256 + threadIdx.x;
    if (e < E) atomicAdd(&deg[ei[E + e]], ew[e]);
}

// ---------------------------------------------------------------------------
// Kernel C: dinv = rsqrt(deg) in place  (deg >= 1 always: self-loop weight 1)
// ---------------------------------------------------------------------------
__global__ __launch_bounds__(256) void k_rsqrt(float* __restrict__ deg, int n) {
    int i = blockIdx.x * 256 + threadIdx.x;
    if (i < n) deg[i] = rsqrtf(deg[i]);
}

// ---------------------------------------------------------------------------
// Kernel D: h = x @ W   (fp32, W staged in LDS, 64 rows/block, 4x8 per thread)
// cols per thread: {tx*4 .. tx*4+3} and {64+tx*4 .. 64+tx*4+3}  (2-way LDS alias, free)
// ---------------------------------------------------------------------------
__global__ __launch_bounds__(256) void k_gemm(const float* __restrict__ x, const float* __restrict__ Wg,
                                              float* __restrict__ h, int nrows) {
    __shared__ float Ws[FEAT * FEAT];
    // stage W (16384 floats) cooperatively
    for (int i = threadIdx.x; i < FEAT * FEAT / 4; i += 256) {
        ((float4*)Ws)[i] = ((const float4*)Wg)[i];
    }
    __syncthreads();

    const int tx = threadIdx.x & 15;   // col group
    const int ty = threadIdx.x >> 4;   // row group (0..15)
    const int j0 = tx * 4;
    const int r0 = blockIdx.x * 64 + ty * 4;

    // clamped row pointers (last block is partial: 50000 = 781*64 + 16)
    const float* xp[4];
#pragma unroll
    for (int i = 0; i < 4; i++) {
        int rr = r0 + i; if (rr >= nrows) rr = 0;
        xp[i] = x + (size_t)rr * FEAT;
    }

    float acc0[4][4] = {{0}};
    float acc1[4][4] = {{0}};

    for (int k = 0; k < FEAT; k += 4) {
        float xv[4][4];
#pragma unroll
        for (int i = 0; i < 4; i++) {
            *(float4*)xv[i] = *(const float4*)&xp[i][k];
        }
#pragma unroll
        for (int kk = 0; kk < 4; kk++) {
            float4 w0 = *(const float4*)&Ws[(k + kk) * FEAT + j0];
            float4 w1 = *(const float4*)&Ws[(k + kk) * FEAT + j0 + 64];
#pragma unroll
            for (int i = 0; i < 4; i++) {
                float a = xv[i][kk];
                acc0[i][0] += a * w0.x; acc0[i][1] += a * w0.y;
                acc0[i][2] += a * w0.z; acc0[i][3] += a * w0.w;
                acc1[i][0] += a * w1.x; acc1[i][1] += a * w1.y;
                acc1[i][2] += a * w1.z; acc1[i][3] += a * w1.w;
            }
        }
    }

#pragma unroll
    for (int i = 0; i < 4; i++) {
        int rr = r0 + i;
        if (rr < nrows) {
            *(float4*)&h[(size_t)rr * FEAT + j0]      = make_float4(acc0[i][0], acc0[i][1], acc0[i][2], acc0[i][3]);
            *(float4*)&h[(size_t)rr * FEAT + j0 + 64] = make_float4(acc1[i][0], acc1[i][1], acc1[i][2], acc1[i][3]);
        }
    }
}

// ---------------------------------------------------------------------------
// Kernel E: edge scatter — acc[col] += h[row] * (dinv[row]*ew*dinv[col])
// 128 lanes per edge (coalesced 512B gather), fp32 global atomics
// ---------------------------------------------------------------------------
__global__ __launch_bounds__(256) void k_scatter(const int* __restrict__ ei, const float* __restrict__ ew,
                                                 const float* __restrict__ dinv, const float* __restrict__ h,
                                                 float* __restrict__ acc, int E) {
    int idx = blockIdx.x * 256 + threadIdx.x;
    int e = idx >> 7;
    int j = idx & 127;
    if (e >= E) return;
    int r = ei[e];
    int c = ei[E + e];
    float nrm = dinv[r] * ew[e] * dinv[c];
    atomicAdd(&acc[(size_t)c * FEAT + j], h[(size_t)r * FEAT + j] * nrm);
}

// ---------------------------------------------------------------------------
// Kernel F: out = ELU(acc + h*dinv^2 + b); accumulate per-column BN partials
// block = 256 threads (2 row-halves x 128 cols), rows_per_block rows each
// ---------------------------------------------------------------------------
__global__ __launch_bounds__(256) void k_elu_bnstat(float* __restrict__ out, const float* __restrict__ h,
                                                    const float* __restrict__ dinv, const float* __restrict__ b,
                                                    float* __restrict__ bnsum, float* __restrict__ bnsq,
                                                    int n, int rows_per_block) {
    int j = threadIdx.x & 127;
    int half = threadIdx.x >> 7;
    int r0 = blockIdx.x * rows_per_block;
    int r1 = r0 + rows_per_block; if (r1 > n) r1 = n;
    float bj = b[j];
    float s = 0.0f, ss = 0.0f;
    for (int r = r0 + half; r < r1; r += 2) {
        float di = dinv[r];
        float v = out[(size_t)r * FEAT + j] + h[(size_t)r * FEAT + j] * di * di + bj;
        v = (v > 0.0f) ? v : expm1f(v);
        out[(size_t)r * FEAT + j] = v;
        s += v; ss += v * v;
    }
    atomicAdd(&bnsum[j], s);
    atomicAdd(&bnsq[j], ss);
}

// ---------------------------------------------------------------------------
// Kernel G: BN finalize — bnsum <- mu, bnsq <- rsqrt(var+eps)
// ---------------------------------------------------------------------------
__global__ void k_bn_finalize(float* __restrict__ bnsum, float* __restrict__ bnsq, float n) {
    int j = threadIdx.x;
    float mu = bnsum[j] / n;
    float var = bnsq[j] / n - mu * mu;
    if (var < 0.0f) var = 0.0f;
    bnsum[j] = mu;
    bnsq[j] = rsqrtf(var + 1e-5f);
}

// ---------------------------------------------------------------------------
// Kernel H: BN apply + LayerNorm, one 64-lane wave per row, 2 cols per lane
// ---------------------------------------------------------------------------
__global__ __launch_bounds__(256) void k_bn_ln(float* __restrict__ out, const float* __restrict__ mu,
                                               const float* __restrict__ rsig,
                                               const float* __restrict__ bng, const float* __restrict__ bnb,
                                               const float* __restrict__ lng, const float* __restrict__ lnb,
                                               int n) {
    int wave = (blockIdx.x * 256 + threadIdx.x) >> 6;
    int lane = threadIdx.x & 63;
    if (wave >= n) return;
    int j0 = lane * 2;
    float2 v = *(const float2*)&out[(size_t)wave * FEAT + j0];
    float t0 = (v.x - mu[j0])     * rsig[j0]     * bng[j0]     + bnb[j0];
    float t1 = (v.y - mu[j0 + 1]) * rsig[j0 + 1] * bng[j0 + 1] + bnb[j0 + 1];
    float s = t0 + t1;
    float ss = t0 * t0 + t1 * t1;
#pragma unroll
    for (int o = 32; o; o >>= 1) {
        s  += __shfl_xor(s, o);
        ss += __shfl_xor(ss, o);
    }
    float m = s * (1.0f / FEAT);
    float var = ss * (1.0f / FEAT) - m * m;
    float r = rsqrtf(var + 1e-5f);
    float o0 = (t0 - m) * r * lng[j0]     + lnb[j0];
    float o1 = (t1 - m) * r * lng[j0 + 1] + lnb[j0 + 1];
    *(float2*)&out[(size_t)wave * FEAT + j0] = make_float2(o0, o1);
}

// ---------------------------------------------------------------------------
extern "C" void kernel_launch(void* const* d_in, const int* in_sizes, int n_in,
                              void* d_out, int out_size, void* d_ws, size_t ws_size,
                              hipStream_t stream) {
    const float* x   = (const float*)d_in[0];
    const int*   ei  = (const int*)  d_in[1];
    const float* ew  = (const float*)d_in[2];
    const float* W   = (const float*)d_in[3];
    const float* b   = (const float*)d_in[4];
    const float* bng = (const float*)d_in[5];
    const float* bnb = (const float*)d_in[6];
    const float* lng = (const float*)d_in[7];
    const float* lnb = (const float*)d_in[8];

    const int N = in_sizes[0] / FEAT;     // 50000
    const int E = in_sizes[2];            // 800000
    const int total = N * FEAT;

    float* out = (float*)d_out;

    // workspace layout: h [N*128] | deg/dinv [N] | bnsum [128] | bnsq [128]
    float* h     = (float*)d_ws;
    float* deg   = h + (size_t)N * FEAT;
    float* bnsum = deg + N;
    float* bnsq  = bnsum + FEAT;

    // A: init
    k_init<<<(total + 255) / 256, 256, 0, stream>>>(out, deg, bnsum, bnsq, total, N);
    // B: degree
    k_deg<<<(E + 255) / 256, 256, 0, stream>>>(ei, ew, deg, E);
    // C: dinv
    k_rsqrt<<<(N + 255) / 256, 256, 0, stream>>>(deg, N);
    // D: h = x @ W
    k_gemm<<<(N + 63) / 64, 256, 0, stream>>>(x, W, h, N);
    // E: edge scatter-add into out
    {
        long long tot = (long long)E * FEAT;
        int blocks = (int)((tot + 255) / 256);
        k_scatter<<<blocks, 256, 0, stream>>>(ei, ew, deg, h, out, E);
    }
    // F: self-loop + bias + ELU + BN partial stats
    {
        int rows_per_block = 100;
        int blocks = (N + rows_per_block - 1) / rows_per_block;
        k_elu_bnstat<<<blocks, 256, 0, stream>>>(out, h, deg, b, bnsum, bnsq, N, rows_per_block);
    }
    // G: BN finalize
    k_bn_finalize<<<1, FEAT, 0, stream>>>(bnsum, bnsq, (float)N);
    // H: BN apply + LayerNorm
    k_bn_ln<<<(N + 3) / 4, 256, 0, stream>>>(out, bnsum, bnsq, bng, bnb, lng, lnb, N);
}

// Round 2
// 375.111 us; speedup vs baseline: 1.3531x; 1.3531x over previous
//
#include <hip/hip_runtime.h>
#include <math.h>

#define FEAT 128

// ---------------------------------------------------------------------------
// Kernel A: init — deg=1.0 (self-loop weight), cnt=0, BN partial sums=0
// (out no longer needs zeroing: k_agg writes every element exactly once)
// ---------------------------------------------------------------------------
__global__ __launch_bounds__(256) void k_init(float* __restrict__ deg, int* __restrict__ cnt,
                                              float* __restrict__ bnsum, float* __restrict__ bnsq,
                                              int n) {
    int i = blockIdx.x * 256 + threadIdx.x;
    if (i < n) { deg[i] = 1.0f; cnt[i] = 0; }
    if (i < FEAT) { bnsum[i] = 0.0f; bnsq[i] = 0.0f; }
}

// ---------------------------------------------------------------------------
// Kernel B: degree (weighted) + histogram (count) over edge targets
// ---------------------------------------------------------------------------
__global__ __launch_bounds__(256) void k_hist_deg(const int* __restrict__ ei, const float* __restrict__ ew,
                                                  float* __restrict__ deg, int* __restrict__ cnt, int E) {
    int e = blockIdx.x * 256 + threadIdx.x;
    if (e < E) {
        int c = ei[E + e];
        atomicAdd(&deg[c], ew[e]);
        atomicAdd(&cnt[c], 1);
    }
}

// ---------------------------------------------------------------------------
// Kernel C: dinv = rsqrt(deg) in place (deg >= 1 always)
// ---------------------------------------------------------------------------
__global__ __launch_bounds__(256) void k_rsqrt(float* __restrict__ deg, int n) {
    int i = blockIdx.x * 256 + threadIdx.x;
    if (i < n) deg[i] = rsqrtf(deg[i]);
}

// ---------------------------------------------------------------------------
// Kernel D: exclusive scan of cnt -> start and cursor (single block, 1024 thr)
// 50000 elems = 49 chunks of 1024, Hillis-Steele in LDS per chunk
// ---------------------------------------------------------------------------
__global__ __launch_bounds__(1024) void k_scan(const int* __restrict__ cnt, int* __restrict__ start,
                                               int* __restrict__ cursor, int n) {
    __shared__ int buf[1024];
    __shared__ int carry;
    int tid = threadIdx.x;
    if (tid == 0) carry = 0;
    __syncthreads();
    for (int base = 0; base < n; base += 1024) {
        int i = base + tid;
        int v = (i < n) ? cnt[i] : 0;
        buf[tid] = v;
        __syncthreads();
#pragma unroll
        for (int o = 1; o < 1024; o <<= 1) {
            int t = (tid >= o) ? buf[tid - o] : 0;
            __syncthreads();
            buf[tid] += t;
            __syncthreads();
        }
        int excl = carry + buf[tid] - v;
        if (i < n) { start[i] = excl; cursor[i] = excl; }
        __syncthreads();              // everyone has read carry
        if (tid == 0) carry += buf[1023];
        __syncthreads();
    }
}

// ---------------------------------------------------------------------------
// Kernel E: fill edge records grouped by target: rec[slot] = {row, ew*dinv[row]}
// ---------------------------------------------------------------------------
__global__ __launch_bounds__(256) void k_fill(const int* __restrict__ ei, const float* __restrict__ ew,
                                              const float* __restrict__ dinv, int* __restrict__ cursor,
                                              int2* __restrict__ rec, int E) {
    int e = blockIdx.x * 256 + threadIdx.x;
    if (e < E) {
        int r = ei[e];
        int c = ei[E + e];
        int slot = atomicAdd(&cursor[c], 1);
        rec[slot] = make_int2(r, __float_as_int(ew[e] * dinv[r]));
    }
}

// ---------------------------------------------------------------------------
// Kernel F: h = x @ W   (fp32, W staged in LDS, 64 rows/block, 4x8 per thread)
// ---------------------------------------------------------------------------
__global__ __launch_bounds__(256) void k_gemm(const float* __restrict__ x, const float* __restrict__ Wg,
                                              float* __restrict__ h, int nrows) {
    __shared__ float Ws[FEAT * FEAT];
    for (int i = threadIdx.x; i < FEAT * FEAT / 4; i += 256) {
        ((float4*)Ws)[i] = ((const float4*)Wg)[i];
    }
    __syncthreads();

    const int tx = threadIdx.x & 15;
    const int ty = threadIdx.x >> 4;
    const int j0 = tx * 4;
    const int r0 = blockIdx.x * 64 + ty * 4;

    const float* xp[4];
#pragma unroll
    for (int i = 0; i < 4; i++) {
        int rr = r0 + i; if (rr >= nrows) rr = 0;
        xp[i] = x + (size_t)rr * FEAT;
    }

    float acc0[4][4] = {{0}};
    float acc1[4][4] = {{0}};

    for (int k = 0; k < FEAT; k += 4) {
        float xv[4][4];
#pragma unroll
        for (int i = 0; i < 4; i++) {
            *(float4*)xv[i] = *(const float4*)&xp[i][k];
        }
#pragma unroll
        for (int kk = 0; kk < 4; kk++) {
            float4 w0 = *(const float4*)&Ws[(k + kk) * FEAT + j0];
            float4 w1 = *(const float4*)&Ws[(k + kk) * FEAT + j0 + 64];
#pragma unroll
            for (int i = 0; i < 4; i++) {
                float a = xv[i][kk];
                acc0[i][0] += a * w0.x; acc0[i][1] += a * w0.y;
                acc0[i][2] += a * w0.z; acc0[i][3] += a * w0.w;
                acc1[i][0] += a * w1.x; acc1[i][1] += a * w1.y;
                acc1[i][2] += a * w1.z; acc1[i][3] += a * w1.w;
            }
        }
    }

#pragma unroll
    for (int i = 0; i < 4; i++) {
        int rr = r0 + i;
        if (rr < nrows) {
            *(float4*)&h[(size_t)rr * FEAT + j0]      = make_float4(acc0[i][0], acc0[i][1], acc0[i][2], acc0[i][3]);
            *(float4*)&h[(size_t)rr * FEAT + j0 + 64] = make_float4(acc1[i][0], acc1[i][1], acc1[i][2], acc1[i][3]);
        }
    }
}

// ---------------------------------------------------------------------------
// Kernel G: aggregate — one 64-lane wave per node, 2 cols/lane, no atomics.
// out[c] = ELU( sum_in-edges h[r]*(dinv_r*ew*dinv_c) + h[c]*dinv_c^2 + b )
// ---------------------------------------------------------------------------
__global__ __launch_bounds__(256) void k_agg(const int* __restrict__ start, const int* __restrict__ cnt,
                                             const int2* __restrict__ rec, const float* __restrict__ dinv,
                                             const float* __restrict__ h, const float* __restrict__ b,
                                             float* __restrict__ out, int n) {
    int wave = (blockIdx.x * 256 + threadIdx.x) >> 6;
    int lane = threadIdx.x & 63;
    if (wave >= n) return;
    const int c = wave;
    const int j0 = lane * 2;
    const int s0 = start[c];
    const int m = cnt[c];
    const float dc = dinv[c];

    float2 hv = *(const float2*)&h[(size_t)c * FEAT + j0];
    float ax = hv.x * dc * dc + b[j0];
    float ay = hv.y * dc * dc + b[j0 + 1];

    int k = 0;
    for (; k + 1 < m; k += 2) {          // 2x unroll: two gathers in flight
        int2 r0 = rec[s0 + k];
        int2 r1 = rec[s0 + k + 1];
        float w0 = __int_as_float(r0.y) * dc;
        float w1 = __int_as_float(r1.y) * dc;
        float2 v0 = *(const float2*)&h[(size_t)r0.x * FEAT + j0];
        float2 v1 = *(const float2*)&h[(size_t)r1.x * FEAT + j0];
        ax += v0.x * w0 + v1.x * w1;
        ay += v0.y * w0 + v1.y * w1;
    }
    if (k < m) {
        int2 r0 = rec[s0 + k];
        float w0 = __int_as_float(r0.y) * dc;
        float2 v0 = *(const float2*)&h[(size_t)r0.x * FEAT + j0];
        ax += v0.x * w0;
        ay += v0.y * w0;
    }

    ax = (ax > 0.0f) ? ax : expm1f(ax);
    ay = (ay > 0.0f) ? ay : expm1f(ay);
    *(float2*)&out[(size_t)c * FEAT + j0] = make_float2(ax, ay);
}

// ---------------------------------------------------------------------------
// Kernel H: BN partial stats over out (read-only pass)
// ---------------------------------------------------------------------------
__global__ __launch_bounds__(256) void k_bnstat(const float* __restrict__ out,
                                                float* __restrict__ bnsum, float* __restrict__ bnsq,
                                                int n, int rows_per_block) {
    int j = threadIdx.x & 127;
    int half = threadIdx.x >> 7;
    int r0 = blockIdx.x * rows_per_block;
    int r1 = r0 + rows_per_block; if (r1 > n) r1 = n;
    float s = 0.0f, ss = 0.0f;
    for (int r = r0 + half; r < r1; r += 2) {
        float v = out[(size_t)r * FEAT + j];
        s += v; ss += v * v;
    }
    atomicAdd(&bnsum[j], s);
    atomicAdd(&bnsq[j], ss);
}

// ---------------------------------------------------------------------------
// Kernel I: BN finalize — bnsum <- mu, bnsq <- rsqrt(var+eps)
// ---------------------------------------------------------------------------
__global__ void k_bn_finalize(float* __restrict__ bnsum, float* __restrict__ bnsq, float n) {
    int j = threadIdx.x;
    float mu = bnsum[j] / n;
    float var = bnsq[j] / n - mu * mu;
    if (var < 0.0f) var = 0.0f;
    bnsum[j] = mu;
    bnsq[j] = rsqrtf(var + 1e-5f);
}

// ---------------------------------------------------------------------------
// Kernel J: BN apply + LayerNorm, one wave per row, 2 cols per lane
// ---------------------------------------------------------------------------
__global__ __launch_bounds__(256) void k_bn_ln(float* __restrict__ out, const float* __restrict__ mu,
                                               const float* __restrict__ rsig,
                                               const float* __restrict__ bng, const float* __restrict__ bnb,
                                               const float* __restrict__ lng, const float* __restrict__ lnb,
                                               int n) {
    int wave = (blockIdx.x * 256 + threadIdx.x) >> 6;
    int lane = threadIdx.x & 63;
    if (wave >= n) return;
    int j0 = lane * 2;
    float2 v = *(const float2*)&out[(size_t)wave * FEAT + j0];
    float t0 = (v.x - mu[j0])     * rsig[j0]     * bng[j0]     + bnb[j0];
    float t1 = (v.y - mu[j0 + 1]) * rsig[j0 + 1] * bng[j0 + 1] + bnb[j0 + 1];
    float s = t0 + t1;
    float ss = t0 * t0 + t1 * t1;
#pragma unroll
    for (int o = 32; o; o >>= 1) {
        s  += __shfl_xor(s, o);
        ss += __shfl_xor(ss, o);
    }
    float m = s * (1.0f / FEAT);
    float var = ss * (1.0f / FEAT) - m * m;
    float r = rsqrtf(var + 1e-5f);
    float o0 = (t0 - m) * r * lng[j0]     + lnb[j0];
    float o1 = (t1 - m) * r * lng[j0 + 1] + lnb[j0 + 1];
    *(float2*)&out[(size_t)wave * FEAT + j0] = make_float2(o0, o1);
}

// ---------------------------------------------------------------------------
extern "C" void kernel_launch(void* const* d_in, const int* in_sizes, int n_in,
                              void* d_out, int out_size, void* d_ws, size_t ws_size,
                              hipStream_t stream) {
    const float* x   = (const float*)d_in[0];
    const int*   ei  = (const int*)  d_in[1];
    const float* ew  = (const float*)d_in[2];
    const float* W   = (const float*)d_in[3];
    const float* b   = (const float*)d_in[4];
    const float* bng = (const float*)d_in[5];
    const float* bnb = (const float*)d_in[6];
    const float* lng = (const float*)d_in[7];
    const float* lnb = (const float*)d_in[8];

    const int N = in_sizes[0] / FEAT;     // 50000
    const int E = in_sizes[2];            // 800000

    float* out = (float*)d_out;

    // workspace layout:
    //   h      [N*128]  floats   (25.6 MB)
    //   rec    [E]      int2     ( 6.4 MB)
    //   deg    [N]      floats
    //   cnt    [N]      ints
    //   start  [N]      ints
    //   cursor [N]      ints
    //   bnsum  [128], bnsq [128] floats
    float* h      = (float*)d_ws;
    int2*  rec    = (int2*)(h + (size_t)N * FEAT);
    float* deg    = (float*)(rec + E);
    int*   cnt    = (int*)(deg + N);
    int*   start  = cnt + N;
    int*   cursor = start + N;
    float* bnsum  = (float*)(cursor + N);
    float* bnsq   = bnsum + FEAT;

    // A: init
    k_init<<<(N + 255) / 256, 256, 0, stream>>>(deg, cnt, bnsum, bnsq, N);
    // B: weighted degree + count histogram
    k_hist_deg<<<(E + 255) / 256, 256, 0, stream>>>(ei, ew, deg, cnt, E);
    // C: dinv
    k_rsqrt<<<(N + 255) / 256, 256, 0, stream>>>(deg, N);
    // D: exclusive scan (single block)
    k_scan<<<1, 1024, 0, stream>>>(cnt, start, cursor, N);
    // F: h = x @ W  (independent of CSR build)
    k_gemm<<<(N + 63) / 64, 256, 0, stream>>>(x, W, h, N);
    // E: fill CSR records (needs dinv)
    k_fill<<<(E + 255) / 256, 256, 0, stream>>>(ei, ew, deg, cursor, rec, E);
    // G: aggregate + self-loop + bias + ELU (no atomics)
    k_agg<<<((N * 64) + 255) / 256, 256, 0, stream>>>(start, cnt, rec, deg, h, b, out, N);
    // H: BN partial stats
    {
        int rows_per_block = 100;
        int blocks = (N + rows_per_block - 1) / rows_per_block;
        k_bnstat<<<blocks, 256, 0, stream>>>(out, bnsum, bnsq, N, rows_per_block);
    }
    // I: BN finalize
    k_bn_finalize<<<1, FEAT, 0, stream>>>(bnsum, bnsq, (float)N);
    // J: BN apply + LayerNorm
    k_bn_ln<<<(N + 3) / 4, 256, 0, stream>>>(out, bnsum, bnsq, bng, bnb, lng, lnb, N);
}

// Round 3
// 299.145 us; speedup vs baseline: 1.6967x; 1.2539x over previous
//
#include <hip/hip_runtime.h>
#include <math.h>

#define FEAT 128

// ---------------------------------------------------------------------------
// Kernel A: init — deg=1.0 (self-loop weight), cnt=0, BN partial sums=0
// ---------------------------------------------------------------------------
__global__ __launch_bounds__(256) void k_init(float* __restrict__ deg, int* __restrict__ cnt,
                                              float* __restrict__ bnsum, float* __restrict__ bnsq,
                                              int n) {
    int i = blockIdx.x * 256 + threadIdx.x;
    if (i < n) { deg[i] = 1.0f; cnt[i] = 0; }
    if (i < FEAT) { bnsum[i] = 0.0f; bnsq[i] = 0.0f; }
}

// ---------------------------------------------------------------------------
// Kernel B: degree (weighted) + histogram (count) over edge targets
// ---------------------------------------------------------------------------
__global__ __launch_bounds__(256) void k_hist_deg(const int* __restrict__ ei, const float* __restrict__ ew,
                                                  float* __restrict__ deg, int* __restrict__ cnt, int E) {
    int e = blockIdx.x * 256 + threadIdx.x;
    if (e < E) {
        int c = ei[E + e];
        atomicAdd(&deg[c], ew[e]);
        atomicAdd(&cnt[c], 1);
    }
}

// ---------------------------------------------------------------------------
// 3-phase parallel exclusive scan of cnt (1024 elems/block, 4 elems/thread)
// ---------------------------------------------------------------------------
// Phase 1: per-block local exclusive scan -> start (local), block sums -> bsum
__global__ __launch_bounds__(256) void k_scan_local(const int* __restrict__ cnt, int* __restrict__ start,
                                                    int* __restrict__ bsum, int n) {
    __shared__ int wtot[4];
    const int tid = threadIdx.x;
    const int i0 = blockIdx.x * 1024 + tid * 4;
    int4 v = make_int4(0, 0, 0, 0);
    if (i0 + 3 < n) v = *(const int4*)&cnt[i0];
    else if (i0 < n) {
        v.x = cnt[i0];
        if (i0 + 1 < n) v.y = cnt[i0 + 1];
        if (i0 + 2 < n) v.z = cnt[i0 + 2];
    }
    const int t = v.x + v.y + v.z + v.w;
    const int lane = tid & 63;
    const int wave = tid >> 6;
    int s = t;
#pragma unroll
    for (int o = 1; o < 64; o <<= 1) {
        int u = __shfl_up(s, o);
        if (lane >= o) s += u;
    }
    if (lane == 63) wtot[wave] = s;
    __syncthreads();
    int woff = 0;
#pragma unroll
    for (int w = 0; w < 4; w++) if (w < wave) woff += wtot[w];
    const int excl = woff + s - t;
    int4 o4 = make_int4(excl, excl + v.x, excl + v.x + v.y, excl + v.x + v.y + v.z);
    if (i0 + 3 < n) *(int4*)&start[i0] = o4;
    else if (i0 < n) {
        start[i0] = o4.x;
        if (i0 + 1 < n) start[i0 + 1] = o4.y;
        if (i0 + 2 < n) start[i0 + 2] = o4.z;
    }
    if (tid == 0) {
        // recompute full block total after sync (wtot complete)
        bsum[blockIdx.x] = 0;  // placeholder, real value written below by tid 255 path
    }
    __syncthreads();
    if (tid == 255) bsum[blockIdx.x] = wtot[0] + wtot[1] + wtot[2] + wtot[3];
}

// Phase 2: exclusive scan of block sums (single wave, chunks of 64)
__global__ __launch_bounds__(64) void k_scan_bsum(int* __restrict__ bsum, int nb) {
    const int lane = threadIdx.x;
    int carry = 0;
    for (int base = 0; base < nb; base += 64) {
        int i = base + lane;
        int v = (i < nb) ? bsum[i] : 0;
        int s = v;
#pragma unroll
        for (int o = 1; o < 64; o <<= 1) {
            int u = __shfl_up(s, o);
            if (lane >= o) s += u;
        }
        if (i < nb) bsum[i] = carry + s - v;
        carry += __shfl(s, 63);
    }
}

// Phase 3: add block offsets -> start & cursor; fused dinv = rsqrt(deg)
__global__ __launch_bounds__(256) void k_scan_add(int* __restrict__ start, int* __restrict__ cursor,
                                                  const int* __restrict__ bsum, float* __restrict__ deg,
                                                  int n) {
    const int i0 = blockIdx.x * 1024 + threadIdx.x * 4;
    const int off = bsum[blockIdx.x];
    if (i0 + 3 < n) {
        int4 s4 = *(int4*)&start[i0];
        s4.x += off; s4.y += off; s4.z += off; s4.w += off;
        *(int4*)&start[i0] = s4;
        *(int4*)&cursor[i0] = s4;
        float4 d4 = *(float4*)&deg[i0];
        d4.x = rsqrtf(d4.x); d4.y = rsqrtf(d4.y);
        d4.z = rsqrtf(d4.z); d4.w = rsqrtf(d4.w);
        *(float4*)&deg[i0] = d4;
    } else {
        for (int i = i0; i < n && i < i0 + 4; i++) {
            int s = start[i] + off;
            start[i] = s; cursor[i] = s;
            deg[i] = rsqrtf(deg[i]);
        }
    }
}

// ---------------------------------------------------------------------------
// Kernel E: fill edge records grouped by target: rec[slot] = {row, ew*dinv[row]}
// ---------------------------------------------------------------------------
__global__ __launch_bounds__(256) void k_fill(const int* __restrict__ ei, const float* __restrict__ ew,
                                              const float* __restrict__ dinv, int* __restrict__ cursor,
                                              int2* __restrict__ rec, int E) {
    int e = blockIdx.x * 256 + threadIdx.x;
    if (e < E) {
        int r = ei[e];
        int c = ei[E + e];
        int slot = atomicAdd(&cursor[c], 1);
        rec[slot] = make_int2(r, __float_as_int(ew[e] * dinv[r]));
    }
}

// ---------------------------------------------------------------------------
// Kernel F: h = x @ W   (fp32, W staged in LDS, 64 rows/block, 4x8 per thread)
// ---------------------------------------------------------------------------
__global__ __launch_bounds__(256) void k_gemm(const float* __restrict__ x, const float* __restrict__ Wg,
                                              float* __restrict__ h, int nrows) {
    __shared__ float Ws[FEAT * FEAT];
    for (int i = threadIdx.x; i < FEAT * FEAT / 4; i += 256) {
        ((float4*)Ws)[i] = ((const float4*)Wg)[i];
    }
    __syncthreads();

    const int tx = threadIdx.x & 15;
    const int ty = threadIdx.x >> 4;
    const int j0 = tx * 4;
    const int r0 = blockIdx.x * 64 + ty * 4;

    const float* xp[4];
#pragma unroll
    for (int i = 0; i < 4; i++) {
        int rr = r0 + i; if (rr >= nrows) rr = 0;
        xp[i] = x + (size_t)rr * FEAT;
    }

    float acc0[4][4] = {{0}};
    float acc1[4][4] = {{0}};

    for (int k = 0; k < FEAT; k += 4) {
        float xv[4][4];
#pragma unroll
        for (int i = 0; i < 4; i++) {
            *(float4*)xv[i] = *(const float4*)&xp[i][k];
        }
#pragma unroll
        for (int kk = 0; kk < 4; kk++) {
            float4 w0 = *(const float4*)&Ws[(k + kk) * FEAT + j0];
            float4 w1 = *(const float4*)&Ws[(k + kk) * FEAT + j0 + 64];
#pragma unroll
            for (int i = 0; i < 4; i++) {
                float a = xv[i][kk];
                acc0[i][0] += a * w0.x; acc0[i][1] += a * w0.y;
                acc0[i][2] += a * w0.z; acc0[i][3] += a * w0.w;
                acc1[i][0] += a * w1.x; acc1[i][1] += a * w1.y;
                acc1[i][2] += a * w1.z; acc1[i][3] += a * w1.w;
            }
        }
    }

#pragma unroll
    for (int i = 0; i < 4; i++) {
        int rr = r0 + i;
        if (rr < nrows) {
            *(float4*)&h[(size_t)rr * FEAT + j0]      = make_float4(acc0[i][0], acc0[i][1], acc0[i][2], acc0[i][3]);
            *(float4*)&h[(size_t)rr * FEAT + j0 + 64] = make_float4(acc1[i][0], acc1[i][1], acc1[i][2], acc1[i][3]);
        }
    }
}

// ---------------------------------------------------------------------------
// Kernel G: aggregate — one 64-lane wave per node, 2 cols/lane, no atomics.
// out[c] = ELU( sum_in-edges h[r]*(dinv_r*ew*dinv_c) + h[c]*dinv_c^2 + b )
// 4 gathers in flight per iteration.
// ---------------------------------------------------------------------------
__global__ __launch_bounds__(256) void k_agg(const int* __restrict__ start, const int* __restrict__ cnt,
                                             const int2* __restrict__ rec, const float* __restrict__ dinv,
                                             const float* __restrict__ h, const float* __restrict__ b,
                                             float* __restrict__ out, int n) {
    int wave = (blockIdx.x * 256 + threadIdx.x) >> 6;
    int lane = threadIdx.x & 63;
    if (wave >= n) return;
    const int c = wave;
    const int j0 = lane * 2;
    const int s0 = start[c];
    const int m = cnt[c];
    const float dc = dinv[c];

    float2 hv = *(const float2*)&h[(size_t)c * FEAT + j0];
    float ax = hv.x * dc * dc + b[j0];
    float ay = hv.y * dc * dc + b[j0 + 1];

    int k = 0;
    for (; k + 3 < m; k += 4) {
        int2 r0 = rec[s0 + k];
        int2 r1 = rec[s0 + k + 1];
        int2 r2 = rec[s0 + k + 2];
        int2 r3 = rec[s0 + k + 3];
        float2 v0 = *(const float2*)&h[(size_t)r0.x * FEAT + j0];
        float2 v1 = *(const float2*)&h[(size_t)r1.x * FEAT + j0];
        float2 v2 = *(const float2*)&h[(size_t)r2.x * FEAT + j0];
        float2 v3 = *(const float2*)&h[(size_t)r3.x * FEAT + j0];
        float w0 = __int_as_float(r0.y) * dc;
        float w1 = __int_as_float(r1.y) * dc;
        float w2 = __int_as_float(r2.y) * dc;
        float w3 = __int_as_float(r3.y) * dc;
        ax += v0.x * w0 + v1.x * w1 + v2.x * w2 + v3.x * w3;
        ay += v0.y * w0 + v1.y * w1 + v2.y * w2 + v3.y * w3;
    }
    for (; k < m; k++) {
        int2 r0 = rec[s0 + k];
        float w0 = __int_as_float(r0.y) * dc;
        float2 v0 = *(const float2*)&h[(size_t)r0.x * FEAT + j0];
        ax += v0.x * w0;
        ay += v0.y * w0;
    }

    ax = (ax > 0.0f) ? ax : expm1f(ax);
    ay = (ay > 0.0f) ? ay : expm1f(ay);
    *(float2*)&out[(size_t)c * FEAT + j0] = make_float2(ax, ay);
}

// ---------------------------------------------------------------------------
// Kernel H: BN partial stats over out (read-only pass)
// ---------------------------------------------------------------------------
__global__ __launch_bounds__(256) void k_bnstat(const float* __restrict__ out,
                                                float* __restrict__ bnsum, float* __restrict__ bnsq,
                                                int n, int rows_per_block) {
    int j = threadIdx.x & 127;
    int half = threadIdx.x >> 7;
    int r0 = blockIdx.x * rows_per_block;
    int r1 = r0 + rows_per_block; if (r1 > n) r1 = n;
    float s = 0.0f, ss = 0.0f;
    for (int r = r0 + half; r < r1; r += 2) {
        float v = out[(size_t)r * FEAT + j];
        s += v; ss += v * v;
    }
    atomicAdd(&bnsum[j], s);
    atomicAdd(&bnsq[j], ss);
}

// ---------------------------------------------------------------------------
// Kernel I: BN finalize — bnsum <- mu, bnsq <- rsqrt(var+eps)
// ---------------------------------------------------------------------------
__global__ void k_bn_finalize(float* __restrict__ bnsum, float* __restrict__ bnsq, float n) {
    int j = threadIdx.x;
    float mu = bnsum[j] / n;
    float var = bnsq[j] / n - mu * mu;
    if (var < 0.0f) var = 0.0f;
    bnsum[j] = mu;
    bnsq[j] = rsqrtf(var + 1e-5f);
}

// ---------------------------------------------------------------------------
// Kernel J: BN apply + LayerNorm, one wave per row, 2 cols per lane
// ---------------------------------------------------------------------------
__global__ __launch_bounds__(256) void k_bn_ln(float* __restrict__ out, const float* __restrict__ mu,
                                               const float* __restrict__ rsig,
                                               const float* __restrict__ bng, const float* __restrict__ bnb,
                                               const float* __restrict__ lng, const float* __restrict__ lnb,
                                               int n) {
    int wave = (blockIdx.x * 256 + threadIdx.x) >> 6;
    int lane = threadIdx.x & 63;
    if (wave >= n) return;
    int j0 = lane * 2;
    float2 v = *(const float2*)&out[(size_t)wave * FEAT + j0];
    float t0 = (v.x - mu[j0])     * rsig[j0]     * bng[j0]     + bnb[j0];
    float t1 = (v.y - mu[j0 + 1]) * rsig[j0 + 1] * bng[j0 + 1] + bnb[j0 + 1];
    float s = t0 + t1;
    float ss = t0 * t0 + t1 * t1;
#pragma unroll
    for (int o = 32; o; o >>= 1) {
        s  += __shfl_xor(s, o);
        ss += __shfl_xor(ss, o);
    }
    float m = s * (1.0f / FEAT);
    float var = ss * (1.0f / FEAT) - m * m;
    float r = rsqrtf(var + 1e-5f);
    float o0 = (t0 - m) * r * lng[j0]     + lnb[j0];
    float o1 = (t1 - m) * r * lng[j0 + 1] + lnb[j0 + 1];
    *(float2*)&out[(size_t)wave * FEAT + j0] = make_float2(o0, o1);
}

// ---------------------------------------------------------------------------
extern "C" void kernel_launch(void* const* d_in, const int* in_sizes, int n_in,
                              void* d_out, int out_size, void* d_ws, size_t ws_size,
                              hipStream_t stream) {
    const float* x   = (const float*)d_in[0];
    const int*   ei  = (const int*)  d_in[1];
    const float* ew  = (const float*)d_in[2];
    const float* W   = (const float*)d_in[3];
    const float* b   = (const float*)d_in[4];
    const float* bng = (const float*)d_in[5];
    const float* bnb = (const float*)d_in[6];
    const float* lng = (const float*)d_in[7];
    const float* lnb = (const float*)d_in[8];

    const int N = in_sizes[0] / FEAT;     // 50000
    const int E = in_sizes[2];            // 800000
    const int NB = (N + 1023) / 1024;     // scan blocks

    float* out = (float*)d_out;

    // workspace layout:
    //   h [N*128] f32 | rec [E] int2 | deg [N] f32 | cnt [N] i32 |
    //   start [N] i32 | cursor [N] i32 | bsum [NB] i32 | bnsum/bnsq [128] f32
    float* h      = (float*)d_ws;
    int2*  rec    = (int2*)(h + (size_t)N * FEAT);
    float* deg    = (float*)(rec + E);
    int*   cnt    = (int*)(deg + N);
    int*   start  = cnt + N;
    int*   cursor = start + N;
    int*   bsum   = cursor + N;
    float* bnsum  = (float*)(bsum + NB);
    float* bnsq   = bnsum + FEAT;

    // A: init
    k_init<<<(N + 255) / 256, 256, 0, stream>>>(deg, cnt, bnsum, bnsq, N);
    // B: weighted degree + count histogram
    k_hist_deg<<<(E + 255) / 256, 256, 0, stream>>>(ei, ew, deg, cnt, E);
    // Scan phase 1/2/3 (+fused rsqrt in phase 3)
    k_scan_local<<<NB, 256, 0, stream>>>(cnt, start, bsum, N);
    k_scan_bsum<<<1, 64, 0, stream>>>(bsum, NB);
    k_scan_add<<<NB, 256, 0, stream>>>(start, cursor, bsum, deg, N);
    // F: h = x @ W  (independent of CSR build)
    k_gemm<<<(N + 63) / 64, 256, 0, stream>>>(x, W, h, N);
    // E: fill CSR records (needs dinv)
    k_fill<<<(E + 255) / 256, 256, 0, stream>>>(ei, ew, deg, cursor, rec, E);
    // G: aggregate + self-loop + bias + ELU (no atomics)
    k_agg<<<((N * 64) + 255) / 256, 256, 0, stream>>>(start, cnt, rec, deg, h, b, out, N);
    // H: BN partial stats
    {
        int rows_per_block = 100;
        int blocks = (N + rows_per_block - 1) / rows_per_block;
        k_bnstat<<<blocks, 256, 0, stream>>>(out, bnsum, bnsq, N, rows_per_block);
    }
    // I: BN finalize
    k_bn_finalize<<<1, FEAT, 0, stream>>>(bnsum, bnsq, (float)N);
    // J: BN apply + LayerNorm
    k_bn_ln<<<(N + 3) / 4, 256, 0, stream>>>(out, bnsum, bnsq, bng, bnb, lng, lnb, N);
}

// Round 4
// 228.737 us; speedup vs baseline: 2.2190x; 1.3078x over previous
//
#include <hip/hip_runtime.h>
#include <math.h>

#define FEAT 128
#define FXS 16777216.0f          // 2^24 fixed-point scale for edge weights
#define FXI (1.0f / 16777216.0f)

// ---------------------------------------------------------------------------
// Kernel A: init — packed = {cnt=0, deg=fx(1.0)} (self-loop), BN sums=0
// ---------------------------------------------------------------------------
__global__ __launch_bounds__(256) void k_init(unsigned long long* __restrict__ packed,
                                              float* __restrict__ bnsum, float* __restrict__ bnsq,
                                              int n) {
    int i = blockIdx.x * 256 + threadIdx.x;
    if (i < n) packed[i] = 16777216ULL;   // fx(1.0), count 0
    if (i < FEAT) { bnsum[i] = 0.0f; bnsq[i] = 0.0f; }
}

// ---------------------------------------------------------------------------
// Kernel B: histogram — ONE 64-bit atomic per edge.
//   packed[c] += (1<<32) | fx(ew)   ; old>>32 is this edge's rank in bucket c
// ---------------------------------------------------------------------------
__global__ __launch_bounds__(256) void k_hist(const int* __restrict__ ei, const float* __restrict__ ew,
                                              unsigned long long* __restrict__ packed,
                                              int* __restrict__ rank, int E) {
    int e = blockIdx.x * 256 + threadIdx.x;
    if (e < E) {
        int c = ei[E + e];
        unsigned fx = (unsigned)(ew[e] * FXS + 0.5f);
        unsigned long long old = atomicAdd(&packed[c], (1ULL << 32) | (unsigned long long)fx);
        rank[e] = (int)(old >> 32);
    }
}

// ---------------------------------------------------------------------------
// 3-phase parallel exclusive scan of counts (1024 elems/block, 4/thread)
// ---------------------------------------------------------------------------
// Phase 1: per-block local exclusive scan -> start (local), block sums -> bsum
__global__ __launch_bounds__(256) void k_scan_local(const unsigned long long* __restrict__ packed,
                                                    int* __restrict__ start, int* __restrict__ bsum, int n) {
    __shared__ int wtot[4];
    const int tid = threadIdx.x;
    const int i0 = blockIdx.x * 1024 + tid * 4;
    int4 v = make_int4(0, 0, 0, 0);
    if (i0 + 3 < n) {
        ulonglong2 p0 = *(const ulonglong2*)&packed[i0];
        ulonglong2 p1 = *(const ulonglong2*)&packed[i0 + 2];
        v = make_int4((int)(p0.x >> 32), (int)(p0.y >> 32), (int)(p1.x >> 32), (int)(p1.y >> 32));
    } else if (i0 < n) {
        v.x = (int)(packed[i0] >> 32);
        if (i0 + 1 < n) v.y = (int)(packed[i0 + 1] >> 32);
        if (i0 + 2 < n) v.z = (int)(packed[i0 + 2] >> 32);
    }
    const int t = v.x + v.y + v.z + v.w;
    const int lane = tid & 63;
    const int wave = tid >> 6;
    int s = t;
#pragma unroll
    for (int o = 1; o < 64; o <<= 1) {
        int u = __shfl_up(s, o);
        if (lane >= o) s += u;
    }
    if (lane == 63) wtot[wave] = s;
    __syncthreads();
    int woff = 0;
#pragma unroll
    for (int w = 0; w < 4; w++) if (w < wave) woff += wtot[w];
    const int excl = woff + s - t;
    int4 o4 = make_int4(excl, excl + v.x, excl + v.x + v.y, excl + v.x + v.y + v.z);
    if (i0 + 3 < n) *(int4*)&start[i0] = o4;
    else if (i0 < n) {
        start[i0] = o4.x;
        if (i0 + 1 < n) start[i0 + 1] = o4.y;
        if (i0 + 2 < n) start[i0 + 2] = o4.z;
    }
    if (tid == 0) bsum[blockIdx.x] = 0;
    __syncthreads();
    if (tid == 255) bsum[blockIdx.x] = wtot[0] + wtot[1] + wtot[2] + wtot[3];
}

// Phase 2: exclusive scan of block sums (single wave, chunks of 64)
__global__ __launch_bounds__(64) void k_scan_bsum(int* __restrict__ bsum, int nb) {
    const int lane = threadIdx.x;
    int carry = 0;
    for (int base = 0; base < nb; base += 64) {
        int i = base + lane;
        int v = (i < nb) ? bsum[i] : 0;
        int s = v;
#pragma unroll
        for (int o = 1; o < 64; o <<= 1) {
            int u = __shfl_up(s, o);
            if (lane >= o) s += u;
        }
        if (i < nb) bsum[i] = carry + s - v;
        carry += __shfl(s, 63);
    }
}

// Phase 3: add block offsets -> start; dinv = rsqrt(fx2float(packed.lo)); start[n]=E
__global__ __launch_bounds__(256) void k_scan_add(int* __restrict__ start, const int* __restrict__ bsum,
                                                  const unsigned long long* __restrict__ packed,
                                                  float* __restrict__ dinv, int n, int E) {
    const int i0 = blockIdx.x * 1024 + threadIdx.x * 4;
    const int off = bsum[blockIdx.x];
    if (i0 == 0) start[n] = E;
    if (i0 + 3 < n) {
        int4 s4 = *(int4*)&start[i0];
        s4.x += off; s4.y += off; s4.z += off; s4.w += off;
        *(int4*)&start[i0] = s4;
        ulonglong2 p0 = *(const ulonglong2*)&packed[i0];
        ulonglong2 p1 = *(const ulonglong2*)&packed[i0 + 2];
        float4 d4;
        d4.x = rsqrtf((float)(unsigned)(p0.x & 0xffffffffULL) * FXI);
        d4.y = rsqrtf((float)(unsigned)(p0.y & 0xffffffffULL) * FXI);
        d4.z = rsqrtf((float)(unsigned)(p1.x & 0xffffffffULL) * FXI);
        d4.w = rsqrtf((float)(unsigned)(p1.y & 0xffffffffULL) * FXI);
        *(float4*)&dinv[i0] = d4;
    } else {
        for (int i = i0; i < n && i < i0 + 4; i++) {
            start[i] += off;
            dinv[i] = rsqrtf((float)(unsigned)(packed[i] & 0xffffffffULL) * FXI);
        }
    }
}

// ---------------------------------------------------------------------------
// Kernel E: fill edge records grouped by target — NO atomics (slot from rank)
// ---------------------------------------------------------------------------
__global__ __launch_bounds__(256) void k_fill(const int* __restrict__ ei, const float* __restrict__ ew,
                                              const float* __restrict__ dinv, const int* __restrict__ start,
                                              const int* __restrict__ rank, int2* __restrict__ rec, int E) {
    int e = blockIdx.x * 256 + threadIdx.x;
    if (e < E) {
        int r = ei[e];
        int c = ei[E + e];
        rec[start[c] + rank[e]] = make_int2(r, __float_as_int(ew[e] * dinv[r]));
    }
}

// ---------------------------------------------------------------------------
// Kernel F: h = x @ W   (fp32, W staged in LDS, 64 rows/block, 4x8 per thread)
// ---------------------------------------------------------------------------
__global__ __launch_bounds__(256) void k_gemm(const float* __restrict__ x, const float* __restrict__ Wg,
                                              float* __restrict__ h, int nrows) {
    __shared__ float Ws[FEAT * FEAT];
    for (int i = threadIdx.x; i < FEAT * FEAT / 4; i += 256) {
        ((float4*)Ws)[i] = ((const float4*)Wg)[i];
    }
    __syncthreads();

    const int tx = threadIdx.x & 15;
    const int ty = threadIdx.x >> 4;
    const int j0 = tx * 4;
    const int r0 = blockIdx.x * 64 + ty * 4;

    const float* xp[4];
#pragma unroll
    for (int i = 0; i < 4; i++) {
        int rr = r0 + i; if (rr >= nrows) rr = 0;
        xp[i] = x + (size_t)rr * FEAT;
    }

    float acc0[4][4] = {{0}};
    float acc1[4][4] = {{0}};

    for (int k = 0; k < FEAT; k += 4) {
        float xv[4][4];
#pragma unroll
        for (int i = 0; i < 4; i++) {
            *(float4*)xv[i] = *(const float4*)&xp[i][k];
        }
#pragma unroll
        for (int kk = 0; kk < 4; kk++) {
            float4 w0 = *(const float4*)&Ws[(k + kk) * FEAT + j0];
            float4 w1 = *(const float4*)&Ws[(k + kk) * FEAT + j0 + 64];
#pragma unroll
            for (int i = 0; i < 4; i++) {
                float a = xv[i][kk];
                acc0[i][0] += a * w0.x; acc0[i][1] += a * w0.y;
                acc0[i][2] += a * w0.z; acc0[i][3] += a * w0.w;
                acc1[i][0] += a * w1.x; acc1[i][1] += a * w1.y;
                acc1[i][2] += a * w1.z; acc1[i][3] += a * w1.w;
            }
        }
    }

#pragma unroll
    for (int i = 0; i < 4; i++) {
        int rr = r0 + i;
        if (rr < nrows) {
            *(float4*)&h[(size_t)rr * FEAT + j0]      = make_float4(acc0[i][0], acc0[i][1], acc0[i][2], acc0[i][3]);
            *(float4*)&h[(size_t)rr * FEAT + j0 + 64] = make_float4(acc1[i][0], acc1[i][1], acc1[i][2], acc1[i][3]);
        }
    }
}

// ---------------------------------------------------------------------------
// Kernel G: aggregate — one 64-lane wave per node, 2 cols/lane, no atomics.
// out[c] = ELU( sum_in-edges h[r]*(dinv_r*ew*dinv_c) + h[c]*dinv_c^2 + b )
// ---------------------------------------------------------------------------
__global__ __launch_bounds__(256) void k_agg(const int* __restrict__ start,
                                             const int2* __restrict__ rec, const float* __restrict__ dinv,
                                             const float* __restrict__ h, const float* __restrict__ b,
                                             float* __restrict__ out, int n) {
    int wave = (blockIdx.x * 256 + threadIdx.x) >> 6;
    int lane = threadIdx.x & 63;
    if (wave >= n) return;
    const int c = wave;
    const int j0 = lane * 2;
    const int s0 = start[c];
    const int m = start[c + 1] - s0;
    const float dc = dinv[c];

    float2 hv = *(const float2*)&h[(size_t)c * FEAT + j0];
    float ax = hv.x * dc * dc + b[j0];
    float ay = hv.y * dc * dc + b[j0 + 1];

    int k = 0;
    for (; k + 3 < m; k += 4) {
        int2 r0 = rec[s0 + k];
        int2 r1 = rec[s0 + k + 1];
        int2 r2 = rec[s0 + k + 2];
        int2 r3 = rec[s0 + k + 3];
        float2 v0 = *(const float2*)&h[(size_t)r0.x * FEAT + j0];
        float2 v1 = *(const float2*)&h[(size_t)r1.x * FEAT + j0];
        float2 v2 = *(const float2*)&h[(size_t)r2.x * FEAT + j0];
        float2 v3 = *(const float2*)&h[(size_t)r3.x * FEAT + j0];
        float w0 = __int_as_float(r0.y) * dc;
        float w1 = __int_as_float(r1.y) * dc;
        float w2 = __int_as_float(r2.y) * dc;
        float w3 = __int_as_float(r3.y) * dc;
        ax += v0.x * w0 + v1.x * w1 + v2.x * w2 + v3.x * w3;
        ay += v0.y * w0 + v1.y * w1 + v2.y * w2 + v3.y * w3;
    }
    for (; k < m; k++) {
        int2 r0 = rec[s0 + k];
        float w0 = __int_as_float(r0.y) * dc;
        float2 v0 = *(const float2*)&h[(size_t)r0.x * FEAT + j0];
        ax += v0.x * w0;
        ay += v0.y * w0;
    }

    ax = (ax > 0.0f) ? ax : expm1f(ax);
    ay = (ay > 0.0f) ? ay : expm1f(ay);
    *(float2*)&out[(size_t)c * FEAT + j0] = make_float2(ax, ay);
}

// ---------------------------------------------------------------------------
// Kernel H: BN partial stats over out (read-only pass)
// ---------------------------------------------------------------------------
__global__ __launch_bounds__(256) void k_bnstat(const float* __restrict__ out,
                                                float* __restrict__ bnsum, float* __restrict__ bnsq,
                                                int n, int rows_per_block) {
    int j = threadIdx.x & 127;
    int half = threadIdx.x >> 7;
    int r0 = blockIdx.x * rows_per_block;
    int r1 = r0 + rows_per_block; if (r1 > n) r1 = n;
    float s = 0.0f, ss = 0.0f;
    for (int r = r0 + half; r < r1; r += 2) {
        float v = out[(size_t)r * FEAT + j];
        s += v; ss += v * v;
    }
    atomicAdd(&bnsum[j], s);
    atomicAdd(&bnsq[j], ss);
}

// ---------------------------------------------------------------------------
// Kernel I: BN finalize — bnsum <- mu, bnsq <- rsqrt(var+eps)
// ---------------------------------------------------------------------------
__global__ void k_bn_finalize(float* __restrict__ bnsum, float* __restrict__ bnsq, float n) {
    int j = threadIdx.x;
    float mu = bnsum[j] / n;
    float var = bnsq[j] / n - mu * mu;
    if (var < 0.0f) var = 0.0f;
    bnsum[j] = mu;
    bnsq[j] = rsqrtf(var + 1e-5f);
}

// ---------------------------------------------------------------------------
// Kernel J: BN apply + LayerNorm, one wave per row, 2 cols per lane
// ---------------------------------------------------------------------------
__global__ __launch_bounds__(256) void k_bn_ln(float* __restrict__ out, const float* __restrict__ mu,
                                               const float* __restrict__ rsig,
                                               const float* __restrict__ bng, const float* __restrict__ bnb,
                                               const float* __restrict__ lng, const float* __restrict__ lnb,
                                               int n) {
    int wave = (blockIdx.x * 256 + threadIdx.x) >> 6;
    int lane = threadIdx.x & 63;
    if (wave >= n) return;
    int j0 = lane * 2;
    float2 v = *(const float2*)&out[(size_t)wave * FEAT + j0];
    float t0 = (v.x - mu[j0])     * rsig[j0]     * bng[j0]     + bnb[j0];
    float t1 = (v.y - mu[j0 + 1]) * rsig[j0 + 1] * bng[j0 + 1] + bnb[j0 + 1];
    float s = t0 + t1;
    float ss = t0 * t0 + t1 * t1;
#pragma unroll
    for (int o = 32; o; o >>= 1) {
        s  += __shfl_xor(s, o);
        ss += __shfl_xor(ss, o);
    }
    float m = s * (1.0f / FEAT);
    float var = ss * (1.0f / FEAT) - m * m;
    float r = rsqrtf(var + 1e-5f);
    float o0 = (t0 - m) * r * lng[j0]     + lnb[j0];
    float o1 = (t1 - m) * r * lng[j0 + 1] + lnb[j0 + 1];
    *(float2*)&out[(size_t)wave * FEAT + j0] = make_float2(o0, o1);
}

// ---------------------------------------------------------------------------
extern "C" void kernel_launch(void* const* d_in, const int* in_sizes, int n_in,
                              void* d_out, int out_size, void* d_ws, size_t ws_size,
                              hipStream_t stream) {
    const float* x   = (const float*)d_in[0];
    const int*   ei  = (const int*)  d_in[1];
    const float* ew  = (const float*)d_in[2];
    const float* W   = (const float*)d_in[3];
    const float* b   = (const float*)d_in[4];
    const float* bng = (const float*)d_in[5];
    const float* bnb = (const float*)d_in[6];
    const float* lng = (const float*)d_in[7];
    const float* lnb = (const float*)d_in[8];

    const int N = in_sizes[0] / FEAT;     // 50000
    const int E = in_sizes[2];            // 800000
    const int NB = (N + 1023) / 1024;     // scan blocks

    float* out = (float*)d_out;

    // workspace layout (all segments 16B-aligned):
    //   h [N*128] f32 | rec [E] int2 | packed [N] u64 | dinv [N] f32 |
    //   rank [E] i32 | start [N+4] i32 | bsum [NB] i32 | bnsum/bnsq [128] f32
    float*              h      = (float*)d_ws;
    int2*               rec    = (int2*)(h + (size_t)N * FEAT);
    unsigned long long* packed = (unsigned long long*)(rec + E);
    float*              dinv   = (float*)(packed + N);
    int*                rank   = (int*)(dinv + N);
    int*                start  = rank + E;
    int*                bsum   = start + N + 4;
    float*              bnsum  = (float*)(bsum + NB);
    float*              bnsq   = bnsum + FEAT;

    // A: init
    k_init<<<(N + 255) / 256, 256, 0, stream>>>(packed, bnsum, bnsq, N);
    // B: packed histogram (1 atomic/edge) + rank capture
    k_hist<<<(E + 255) / 256, 256, 0, stream>>>(ei, ew, packed, rank, E);
    // Scan phase 1/2/3 (+fused dinv in phase 3)
    k_scan_local<<<NB, 256, 0, stream>>>(packed, start, bsum, N);
    k_scan_bsum<<<1, 64, 0, stream>>>(bsum, NB);
    k_scan_add<<<NB, 256, 0, stream>>>(start, bsum, packed, dinv, N, E);
    // F: h = x @ W  (independent of CSR build)
    k_gemm<<<(N + 63) / 64, 256, 0, stream>>>(x, W, h, N);
    // E: fill CSR records (no atomics)
    k_fill<<<(E + 255) / 256, 256, 0, stream>>>(ei, ew, dinv, start, rank, rec, E);
    // G: aggregate + self-loop + bias + ELU (no atomics)
    k_agg<<<((N * 64) + 255) / 256, 256, 0, stream>>>(start, rec, dinv, h, b, out, N);
    // H: BN partial stats
    {
        int rows_per_block = 100;
        int blocks = (N + rows_per_block - 1) / rows_per_block;
        k_bnstat<<<blocks, 256, 0, stream>>>(out, bnsum, bnsq, N, rows_per_block);
    }
    // I: BN finalize
    k_bn_finalize<<<1, FEAT, 0, stream>>>(bnsum, bnsq, (float)N);
    // J: BN apply + LayerNorm
    k_bn_ln<<<(N + 3) / 4, 256, 0, stream>>>(out, bnsum, bnsq, bng, bnb, lng, lnb, N);
}

// Round 5
// 205.180 us; speedup vs baseline: 2.4738x; 1.1148x over previous
//
#include <hip/hip_runtime.h>
#include <math.h>

#define FEAT 128
#define FXS 16777216.0f          // 2^24 fixed-point scale for edge weights
#define FXI (1.0f / 16777216.0f)

// bf16 helpers (bit-level, RNE pack / exact unpack)
__device__ inline unsigned pkbf(float a, float b) {
    unsigned ua = __float_as_uint(a), ub = __float_as_uint(b);
    ua += 0x7fffu + ((ua >> 16) & 1u);
    ub += 0x7fffu + ((ub >> 16) & 1u);
    return (ua >> 16) | (ub & 0xffff0000u);
}
__device__ inline float2 upbf(unsigned v) {
    return make_float2(__uint_as_float(v << 16), __uint_as_float(v & 0xffff0000u));
}

// ---------------------------------------------------------------------------
// Kernel A: init — packed = {cnt=0, deg=fx(1.0)} (self-loop), BN sums=0
// ---------------------------------------------------------------------------
__global__ __launch_bounds__(256) void k_init(unsigned long long* __restrict__ packed,
                                              float* __restrict__ bnsum, float* __restrict__ bnsq,
                                              int n) {
    int i = blockIdx.x * 256 + threadIdx.x;
    if (i < n) packed[i] = 16777216ULL;   // fx(1.0), count 0
    if (i < FEAT) { bnsum[i] = 0.0f; bnsq[i] = 0.0f; }
}

// ---------------------------------------------------------------------------
// Kernel B: histogram — ONE 64-bit atomic per edge; old>>32 = rank in bucket
// ---------------------------------------------------------------------------
__global__ __launch_bounds__(256) void k_hist(const int* __restrict__ ei, const float* __restrict__ ew,
                                              unsigned long long* __restrict__ packed,
                                              int* __restrict__ rank, int E) {
    int e = blockIdx.x * 256 + threadIdx.x;
    if (e < E) {
        int c = ei[E + e];
        unsigned fx = (unsigned)(ew[e] * FXS + 0.5f);
        unsigned long long old = atomicAdd(&packed[c], (1ULL << 32) | (unsigned long long)fx);
        rank[e] = (int)(old >> 32);
    }
}

// ---------------------------------------------------------------------------
// 3-phase parallel exclusive scan of counts (1024 elems/block, 4/thread)
// ---------------------------------------------------------------------------
__global__ __launch_bounds__(256) void k_scan_local(const unsigned long long* __restrict__ packed,
                                                    int* __restrict__ start, int* __restrict__ bsum, int n) {
    __shared__ int wtot[4];
    const int tid = threadIdx.x;
    const int i0 = blockIdx.x * 1024 + tid * 4;
    int4 v = make_int4(0, 0, 0, 0);
    if (i0 + 3 < n) {
        ulonglong2 p0 = *(const ulonglong2*)&packed[i0];
        ulonglong2 p1 = *(const ulonglong2*)&packed[i0 + 2];
        v = make_int4((int)(p0.x >> 32), (int)(p0.y >> 32), (int)(p1.x >> 32), (int)(p1.y >> 32));
    } else if (i0 < n) {
        v.x = (int)(packed[i0] >> 32);
        if (i0 + 1 < n) v.y = (int)(packed[i0 + 1] >> 32);
        if (i0 + 2 < n) v.z = (int)(packed[i0 + 2] >> 32);
    }
    const int t = v.x + v.y + v.z + v.w;
    const int lane = tid & 63;
    const int wave = tid >> 6;
    int s = t;
#pragma unroll
    for (int o = 1; o < 64; o <<= 1) {
        int u = __shfl_up(s, o);
        if (lane >= o) s += u;
    }
    if (lane == 63) wtot[wave] = s;
    __syncthreads();
    int woff = 0;
#pragma unroll
    for (int w = 0; w < 4; w++) if (w < wave) woff += wtot[w];
    const int excl = woff + s - t;
    int4 o4 = make_int4(excl, excl + v.x, excl + v.x + v.y, excl + v.x + v.y + v.z);
    if (i0 + 3 < n) *(int4*)&start[i0] = o4;
    else if (i0 < n) {
        start[i0] = o4.x;
        if (i0 + 1 < n) start[i0 + 1] = o4.y;
        if (i0 + 2 < n) start[i0 + 2] = o4.z;
    }
    if (tid == 0) bsum[blockIdx.x] = 0;
    __syncthreads();
    if (tid == 255) bsum[blockIdx.x] = wtot[0] + wtot[1] + wtot[2] + wtot[3];
}

__global__ __launch_bounds__(64) void k_scan_bsum(int* __restrict__ bsum, int nb) {
    const int lane = threadIdx.x;
    int carry = 0;
    for (int base = 0; base < nb; base += 64) {
        int i = base + lane;
        int v = (i < nb) ? bsum[i] : 0;
        int s = v;
#pragma unroll
        for (int o = 1; o < 64; o <<= 1) {
            int u = __shfl_up(s, o);
            if (lane >= o) s += u;
        }
        if (i < nb) bsum[i] = carry + s - v;
        carry += __shfl(s, 63);
    }
}

__global__ __launch_bounds__(256) void k_scan_add(int* __restrict__ start, const int* __restrict__ bsum,
                                                  const unsigned long long* __restrict__ packed,
                                                  float* __restrict__ dinv, int n, int E) {
    const int i0 = blockIdx.x * 1024 + threadIdx.x * 4;
    const int off = bsum[blockIdx.x];
    if (i0 == 0) start[n] = E;
    if (i0 + 3 < n) {
        int4 s4 = *(int4*)&start[i0];
        s4.x += off; s4.y += off; s4.z += off; s4.w += off;
        *(int4*)&start[i0] = s4;
        ulonglong2 p0 = *(const ulonglong2*)&packed[i0];
        ulonglong2 p1 = *(const ulonglong2*)&packed[i0 + 2];
        float4 d4;
        d4.x = rsqrtf((float)(unsigned)(p0.x & 0xffffffffULL) * FXI);
        d4.y = rsqrtf((float)(unsigned)(p0.y & 0xffffffffULL) * FXI);
        d4.z = rsqrtf((float)(unsigned)(p1.x & 0xffffffffULL) * FXI);
        d4.w = rsqrtf((float)(unsigned)(p1.y & 0xffffffffULL) * FXI);
        *(float4*)&dinv[i0] = d4;
    } else {
        for (int i = i0; i < n && i < i0 + 4; i++) {
            start[i] += off;
            dinv[i] = rsqrtf((float)(unsigned)(packed[i] & 0xffffffffULL) * FXI);
        }
    }
}

// ---------------------------------------------------------------------------
// Kernel E: fill edge records grouped by target — NO atomics (slot from rank)
// ---------------------------------------------------------------------------
__global__ __launch_bounds__(256) void k_fill(const int* __restrict__ ei, const float* __restrict__ ew,
                                              const float* __restrict__ dinv, const int* __restrict__ start,
                                              const int* __restrict__ rank, int2* __restrict__ rec, int E) {
    int e = blockIdx.x * 256 + threadIdx.x;
    if (e < E) {
        int r = ei[e];
        int c = ei[E + e];
        rec[start[c] + rank[e]] = make_int2(r, __float_as_int(ew[e] * dinv[r]));
    }
}

// ---------------------------------------------------------------------------
// Kernel F: h = x @ W, output packed bf16 (RNE). W in LDS fp32.
// ---------------------------------------------------------------------------
__global__ __launch_bounds__(256) void k_gemm(const float* __restrict__ x, const float* __restrict__ Wg,
                                              unsigned* __restrict__ hb, int nrows) {
    __shared__ float Ws[FEAT * FEAT];
    for (int i = threadIdx.x; i < FEAT * FEAT / 4; i += 256) {
        ((float4*)Ws)[i] = ((const float4*)Wg)[i];
    }
    __syncthreads();

    const int tx = threadIdx.x & 15;
    const int ty = threadIdx.x >> 4;
    const int j0 = tx * 4;
    const int r0 = blockIdx.x * 64 + ty * 4;

    const float* xp[4];
#pragma unroll
    for (int i = 0; i < 4; i++) {
        int rr = r0 + i; if (rr >= nrows) rr = 0;
        xp[i] = x + (size_t)rr * FEAT;
    }

    float acc0[4][4] = {{0}};
    float acc1[4][4] = {{0}};

    for (int k = 0; k < FEAT; k += 4) {
        float xv[4][4];
#pragma unroll
        for (int i = 0; i < 4; i++) {
            *(float4*)xv[i] = *(const float4*)&xp[i][k];
        }
#pragma unroll
        for (int kk = 0; kk < 4; kk++) {
            float4 w0 = *(const float4*)&Ws[(k + kk) * FEAT + j0];
            float4 w1 = *(const float4*)&Ws[(k + kk) * FEAT + j0 + 64];
#pragma unroll
            for (int i = 0; i < 4; i++) {
                float a = xv[i][kk];
                acc0[i][0] += a * w0.x; acc0[i][1] += a * w0.y;
                acc0[i][2] += a * w0.z; acc0[i][3] += a * w0.w;
                acc1[i][0] += a * w1.x; acc1[i][1] += a * w1.y;
                acc1[i][2] += a * w1.z; acc1[i][3] += a * w1.w;
            }
        }
    }

    // hb layout: 64 uints per row (128 bf16). This thread owns uints
    // [j0/2, j0/2+1] and [32+j0/2, 32+j0/2+1].
#pragma unroll
    for (int i = 0; i < 4; i++) {
        int rr = r0 + i;
        if (rr < nrows) {
            unsigned* rowp = hb + (size_t)rr * (FEAT / 2);
            *(uint2*)&rowp[j0 >> 1] = make_uint2(pkbf(acc0[i][0], acc0[i][1]), pkbf(acc0[i][2], acc0[i][3]));
            *(uint2*)&rowp[32 + (j0 >> 1)] = make_uint2(pkbf(acc1[i][0], acc1[i][1]), pkbf(acc1[i][2], acc1[i][3]));
        }
    }
}

// ---------------------------------------------------------------------------
// Kernel G: aggregate — one wave per node, 2 cols/lane (one bf16x2 word),
// 8 gathers in flight. out[c] = ELU( sum h[r]*nrm + h[c]*dc^2 + b )
// ---------------------------------------------------------------------------
__global__ __launch_bounds__(256) void k_agg(const int* __restrict__ start,
                                             const int2* __restrict__ rec, const float* __restrict__ dinv,
                                             const unsigned* __restrict__ hb, const float* __restrict__ b,
                                             float* __restrict__ out, int n) {
    int wave = (blockIdx.x * 256 + threadIdx.x) >> 6;
    int lane = threadIdx.x & 63;
    if (wave >= n) return;
    const int c = wave;
    const int j0 = lane * 2;
    const int s0 = start[c];
    const int m = start[c + 1] - s0;
    const float dc = dinv[c];

    float2 hv = upbf(hb[(size_t)c * 64 + lane]);
    float ax = hv.x * dc * dc + b[j0];
    float ay = hv.y * dc * dc + b[j0 + 1];

    int k = 0;
    for (; k + 7 < m; k += 8) {
        int2 r[8];
        unsigned g[8];
#pragma unroll
        for (int u = 0; u < 8; u++) r[u] = rec[s0 + k + u];
#pragma unroll
        for (int u = 0; u < 8; u++) g[u] = hb[(size_t)r[u].x * 64 + lane];
#pragma unroll
        for (int u = 0; u < 8; u++) {
            float w = __int_as_float(r[u].y) * dc;
            float2 v = upbf(g[u]);
            ax += v.x * w;
            ay += v.y * w;
        }
    }
    for (; k + 3 < m; k += 4) {
        int2 r[4];
        unsigned g[4];
#pragma unroll
        for (int u = 0; u < 4; u++) r[u] = rec[s0 + k + u];
#pragma unroll
        for (int u = 0; u < 4; u++) g[u] = hb[(size_t)r[u].x * 64 + lane];
#pragma unroll
        for (int u = 0; u < 4; u++) {
            float w = __int_as_float(r[u].y) * dc;
            float2 v = upbf(g[u]);
            ax += v.x * w;
            ay += v.y * w;
        }
    }
    for (; k < m; k++) {
        int2 r0 = rec[s0 + k];
        float w = __int_as_float(r0.y) * dc;
        float2 v = upbf(hb[(size_t)r0.x * 64 + lane]);
        ax += v.x * w;
        ay += v.y * w;
    }

    ax = (ax > 0.0f) ? ax : expm1f(ax);
    ay = (ay > 0.0f) ? ay : expm1f(ay);
    *(float2*)&out[(size_t)c * FEAT + j0] = make_float2(ax, ay);
}

// ---------------------------------------------------------------------------
// Kernel H: BN partial stats over out (read-only pass)
// ---------------------------------------------------------------------------
__global__ __launch_bounds__(256) void k_bnstat(const float* __restrict__ out,
                                                float* __restrict__ bnsum, float* __restrict__ bnsq,
                                                int n, int rows_per_block) {
    int j = threadIdx.x & 127;
    int half = threadIdx.x >> 7;
    int r0 = blockIdx.x * rows_per_block;
    int r1 = r0 + rows_per_block; if (r1 > n) r1 = n;
    float s = 0.0f, ss = 0.0f;
    for (int r = r0 + half; r < r1; r += 2) {
        float v = out[(size_t)r * FEAT + j];
        s += v; ss += v * v;
    }
    atomicAdd(&bnsum[j], s);
    atomicAdd(&bnsq[j], ss);
}

// ---------------------------------------------------------------------------
// Kernel I: BN finalize — bnsum <- mu, bnsq <- rsqrt(var+eps)
// ---------------------------------------------------------------------------
__global__ void k_bn_finalize(float* __restrict__ bnsum, float* __restrict__ bnsq, float n) {
    int j = threadIdx.x;
    float mu = bnsum[j] / n;
    float var = bnsq[j] / n - mu * mu;
    if (var < 0.0f) var = 0.0f;
    bnsum[j] = mu;
    bnsq[j] = rsqrtf(var + 1e-5f);
}

// ---------------------------------------------------------------------------
// Kernel J: BN apply + LayerNorm, one wave per row, 2 cols per lane
// ---------------------------------------------------------------------------
__global__ __launch_bounds__(256) void k_bn_ln(float* __restrict__ out, const float* __restrict__ mu,
                                               const float* __restrict__ rsig,
                                               const float* __restrict__ bng, const float* __restrict__ bnb,
                                               const float* __restrict__ lng, const float* __restrict__ lnb,
                                               int n) {
    int wave = (blockIdx.x * 256 + threadIdx.x) >> 6;
    int lane = threadIdx.x & 63;
    if (wave >= n) return;
    int j0 = lane * 2;
    float2 v = *(const float2*)&out[(size_t)wave * FEAT + j0];
    float t0 = (v.x - mu[j0])     * rsig[j0]     * bng[j0]     + bnb[j0];
    float t1 = (v.y - mu[j0 + 1]) * rsig[j0 + 1] * bng[j0 + 1] + bnb[j0 + 1];
    float s = t0 + t1;
    float ss = t0 * t0 + t1 * t1;
#pragma unroll
    for (int o = 32; o; o >>= 1) {
        s  += __shfl_xor(s, o);
        ss += __shfl_xor(ss, o);
    }
    float m = s * (1.0f / FEAT);
    float var = ss * (1.0f / FEAT) - m * m;
    float r = rsqrtf(var + 1e-5f);
    float o0 = (t0 - m) * r * lng[j0]     + lnb[j0];
    float o1 = (t1 - m) * r * lng[j0 + 1] + lnb[j0 + 1];
    *(float2*)&out[(size_t)wave * FEAT + j0] = make_float2(o0, o1);
}

// ---------------------------------------------------------------------------
extern "C" void kernel_launch(void* const* d_in, const int* in_sizes, int n_in,
                              void* d_out, int out_size, void* d_ws, size_t ws_size,
                              hipStream_t stream) {
    const float* x   = (const float*)d_in[0];
    const int*   ei  = (const int*)  d_in[1];
    const float* ew  = (const float*)d_in[2];
    const float* W   = (const float*)d_in[3];
    const float* b   = (const float*)d_in[4];
    const float* bng = (const float*)d_in[5];
    const float* bnb = (const float*)d_in[6];
    const float* lng = (const float*)d_in[7];
    const float* lnb = (const float*)d_in[8];

    const int N = in_sizes[0] / FEAT;     // 50000
    const int E = in_sizes[2];            // 800000
    const int NB = (N + 1023) / 1024;     // scan blocks

    float* out = (float*)d_out;

    // workspace layout (16B-aligned segments):
    //   hb [N*64] u32 (bf16x2, 12.8MB) | rec [E] int2 | packed [N] u64 |
    //   dinv [N] f32 | rank [E] i32 | start [N+4] i32 | bsum [NB] i32 |
    //   bnsum/bnsq [128] f32
    unsigned*           hb     = (unsigned*)d_ws;
    int2*               rec    = (int2*)(hb + (size_t)N * 64);
    unsigned long long* packed = (unsigned long long*)(rec + E);
    float*              dinv   = (float*)(packed + N);
    int*                rank   = (int*)(dinv + N);
    int*                start  = rank + E;
    int*                bsum   = start + N + 4;
    float*              bnsum  = (float*)(bsum + NB);
    float*              bnsq   = bnsum + FEAT;

    // A: init
    k_init<<<(N + 255) / 256, 256, 0, stream>>>(packed, bnsum, bnsq, N);
    // B: packed histogram (1 atomic/edge) + rank capture
    k_hist<<<(E + 255) / 256, 256, 0, stream>>>(ei, ew, packed, rank, E);
    // Scan phase 1/2/3 (+fused dinv in phase 3)
    k_scan_local<<<NB, 256, 0, stream>>>(packed, start, bsum, N);
    k_scan_bsum<<<1, 64, 0, stream>>>(bsum, NB);
    k_scan_add<<<NB, 256, 0, stream>>>(start, bsum, packed, dinv, N, E);
    // F: h = x @ W (bf16 out)
    k_gemm<<<(N + 63) / 64, 256, 0, stream>>>(x, W, hb, N);
    // E: fill CSR records (no atomics)
    k_fill<<<(E + 255) / 256, 256, 0, stream>>>(ei, ew, dinv, start, rank, rec, E);
    // G: aggregate + self-loop + bias + ELU (no atomics)
    k_agg<<<((N * 64) + 255) / 256, 256, 0, stream>>>(start, rec, dinv, hb, b, out, N);
    // H: BN partial stats
    {
        int rows_per_block = 100;
        int blocks = (N + rows_per_block - 1) / rows_per_block;
        k_bnstat<<<blocks, 256, 0, stream>>>(out, bnsum, bnsq, N, rows_per_block);
    }
    // I: BN finalize
    k_bn_finalize<<<1, FEAT, 0, stream>>>(bnsum, bnsq, (float)N);
    // J: BN apply + LayerNorm
    k_bn_ln<<<(N + 3) / 4, 256, 0, stream>>>(out, bnsum, bnsq, bng, bnb, lng, lnb, N);
}

// Round 6
// 180.474 us; speedup vs baseline: 2.8124x; 1.1369x over previous
//
#include <hip/hip_runtime.h>
#include <math.h>

#define FEAT 128
#define FXS 16777216.0f          // 2^24 fixed-point scale for edge weights
#define FXI (1.0f / 16777216.0f)

typedef __attribute__((ext_vector_type(8)))  short short8;
typedef __attribute__((ext_vector_type(16))) float f32x16;

// bf16 helpers (bit-level, RNE pack / exact unpack)
__device__ inline unsigned pkbf(float a, float b) {
    unsigned ua = __float_as_uint(a), ub = __float_as_uint(b);
    ua += 0x7fffu + ((ua >> 16) & 1u);
    ub += 0x7fffu + ((ub >> 16) & 1u);
    return (ua >> 16) | (ub & 0xffff0000u);
}
__device__ inline unsigned short bf16of(float a) {
    unsigned ua = __float_as_uint(a);
    ua += 0x7fffu + ((ua >> 16) & 1u);
    return (unsigned short)(ua >> 16);
}
__device__ inline float2 upbf(unsigned v) {
    return make_float2(__uint_as_float(v << 16), __uint_as_float(v & 0xffff0000u));
}

// ---------------------------------------------------------------------------
// Kernel A: init — packed = {cnt=0, deg=fx(1.0)} (self-loop), BN sums=0
// ---------------------------------------------------------------------------
__global__ __launch_bounds__(256) void k_init(unsigned long long* __restrict__ packed,
                                              float* __restrict__ bnsum, float* __restrict__ bnsq,
                                              int n) {
    int i = blockIdx.x * 256 + threadIdx.x;
    if (i < n) packed[i] = 16777216ULL;   // fx(1.0), count 0
    if (i < FEAT) { bnsum[i] = 0.0f; bnsq[i] = 0.0f; }
}

// ---------------------------------------------------------------------------
// Kernel B: histogram — ONE 64-bit atomic per edge; old>>32 = rank in bucket
// ---------------------------------------------------------------------------
__global__ __launch_bounds__(256) void k_hist(const int* __restrict__ ei, const float* __restrict__ ew,
                                              unsigned long long* __restrict__ packed,
                                              int* __restrict__ rank, int E) {
    int e = blockIdx.x * 256 + threadIdx.x;
    if (e < E) {
        int c = ei[E + e];
        unsigned fx = (unsigned)(ew[e] * FXS + 0.5f);
        unsigned long long old = atomicAdd(&packed[c], (1ULL << 32) | (unsigned long long)fx);
        rank[e] = (int)(old >> 32);
    }
}

// ---------------------------------------------------------------------------
// 3-phase parallel exclusive scan of counts (1024 elems/block, 4/thread)
// ---------------------------------------------------------------------------
__global__ __launch_bounds__(256) void k_scan_local(const unsigned long long* __restrict__ packed,
                                                    int* __restrict__ start, int* __restrict__ bsum, int n) {
    __shared__ int wtot[4];
    const int tid = threadIdx.x;
    const int i0 = blockIdx.x * 1024 + tid * 4;
    int4 v = make_int4(0, 0, 0, 0);
    if (i0 + 3 < n) {
        ulonglong2 p0 = *(const ulonglong2*)&packed[i0];
        ulonglong2 p1 = *(const ulonglong2*)&packed[i0 + 2];
        v = make_int4((int)(p0.x >> 32), (int)(p0.y >> 32), (int)(p1.x >> 32), (int)(p1.y >> 32));
    } else if (i0 < n) {
        v.x = (int)(packed[i0] >> 32);
        if (i0 + 1 < n) v.y = (int)(packed[i0 + 1] >> 32);
        if (i0 + 2 < n) v.z = (int)(packed[i0 + 2] >> 32);
    }
    const int t = v.x + v.y + v.z + v.w;
    const int lane = tid & 63;
    const int wave = tid >> 6;
    int s = t;
#pragma unroll
    for (int o = 1; o < 64; o <<= 1) {
        int u = __shfl_up(s, o);
        if (lane >= o) s += u;
    }
    if (lane == 63) wtot[wave] = s;
    __syncthreads();
    int woff = 0;
#pragma unroll
    for (int w = 0; w < 4; w++) if (w < wave) woff += wtot[w];
    const int excl = woff + s - t;
    int4 o4 = make_int4(excl, excl + v.x, excl + v.x + v.y, excl + v.x + v.y + v.z);
    if (i0 + 3 < n) *(int4*)&start[i0] = o4;
    else if (i0 < n) {
        start[i0] = o4.x;
        if (i0 + 1 < n) start[i0 + 1] = o4.y;
        if (i0 + 2 < n) start[i0 + 2] = o4.z;
    }
    if (tid == 0) bsum[blockIdx.x] = 0;
    __syncthreads();
    if (tid == 255) bsum[blockIdx.x] = wtot[0] + wtot[1] + wtot[2] + wtot[3];
}

__global__ __launch_bounds__(64) void k_scan_bsum(int* __restrict__ bsum, int nb) {
    const int lane = threadIdx.x;
    int carry = 0;
    for (int base = 0; base < nb; base += 64) {
        int i = base + lane;
        int v = (i < nb) ? bsum[i] : 0;
        int s = v;
#pragma unroll
        for (int o = 1; o < 64; o <<= 1) {
            int u = __shfl_up(s, o);
            if (lane >= o) s += u;
        }
        if (i < nb) bsum[i] = carry + s - v;
        carry += __shfl(s, 63);
    }
}

__global__ __launch_bounds__(256) void k_scan_add(int* __restrict__ start, const int* __restrict__ bsum,
                                                  const unsigned long long* __restrict__ packed,
                                                  float* __restrict__ dinv, int n, int E) {
    const int i0 = blockIdx.x * 1024 + threadIdx.x * 4;
    const int off = bsum[blockIdx.x];
    if (i0 == 0) start[n] = E;
    if (i0 + 3 < n) {
        int4 s4 = *(int4*)&start[i0];
        s4.x += off; s4.y += off; s4.z += off; s4.w += off;
        *(int4*)&start[i0] = s4;
        ulonglong2 p0 = *(const ulonglong2*)&packed[i0];
        ulonglong2 p1 = *(const ulonglong2*)&packed[i0 + 2];
        float4 d4;
        d4.x = rsqrtf((float)(unsigned)(p0.x & 0xffffffffULL) * FXI);
        d4.y = rsqrtf((float)(unsigned)(p0.y & 0xffffffffULL) * FXI);
        d4.z = rsqrtf((float)(unsigned)(p1.x & 0xffffffffULL) * FXI);
        d4.w = rsqrtf((float)(unsigned)(p1.y & 0xffffffffULL) * FXI);
        *(float4*)&dinv[i0] = d4;
    } else {
        for (int i = i0; i < n && i < i0 + 4; i++) {
            start[i] += off;
            dinv[i] = rsqrtf((float)(unsigned)(packed[i] & 0xffffffffULL) * FXI);
        }
    }
}

// ---------------------------------------------------------------------------
// Kernel E: fill edge records grouped by target — NO atomics (slot from rank)
// ---------------------------------------------------------------------------
__global__ __launch_bounds__(256) void k_fill(const int* __restrict__ ei, const float* __restrict__ ew,
                                              const float* __restrict__ dinv, const int* __restrict__ start,
                                              const int* __restrict__ rank, int2* __restrict__ rec, int E) {
    int e = blockIdx.x * 256 + threadIdx.x;
    if (e < E) {
        int r = ei[e];
        int c = ei[E + e];
        rec[start[c] + rank[e]] = make_int2(r, __float_as_int(ew[e] * dinv[r]));
    }
}

// ---------------------------------------------------------------------------
// Kernel F: h = x @ W via MFMA 32x32x16 bf16.
// Block = 4 waves, 128 rows; wave w: rows base+w*32..+31, all 128 cols.
// W staged in LDS pre-swizzled into B-fragment order:
//   wlds[ct][ks][lane] (4 uints = 8 bf16) = W[ks*16 + 8*(lane>>5) + i][ct*32 + (lane&31)]
// A-frag: lane holds x[row=base+w*32+(lane&31)][ks*16 + 8*(lane>>5) + i], i=0..7
// C/D layout (verified m74/m101): col=lane&31, row=(reg&3)+8*(reg>>2)+4*(lane>>5)
// ---------------------------------------------------------------------------
__global__ __launch_bounds__(256) void k_gemm_mfma(const float* __restrict__ x,
                                                   const float* __restrict__ Wg,
                                                   unsigned short* __restrict__ hb, int nrows) {
    __shared__ unsigned wlds[4][8][64][4];   // 32 KB
    const int tid = threadIdx.x;

    // stage W (fp32 global, coalesced per 32-lane group) -> bf16 fragment order
    for (int idx = tid; idx < 4 * 8 * 64; idx += 256) {
        int lane = idx & 63;
        int ks = (idx >> 6) & 7;
        int ct = idx >> 9;
        int krow = ks * 16 + 8 * (lane >> 5);
        int col = ct * 32 + (lane & 31);
        unsigned u0 = pkbf(Wg[(krow + 0) * FEAT + col], Wg[(krow + 1) * FEAT + col]);
        unsigned u1 = pkbf(Wg[(krow + 2) * FEAT + col], Wg[(krow + 3) * FEAT + col]);
        unsigned u2 = pkbf(Wg[(krow + 4) * FEAT + col], Wg[(krow + 5) * FEAT + col]);
        unsigned u3 = pkbf(Wg[(krow + 6) * FEAT + col], Wg[(krow + 7) * FEAT + col]);
        *(uint4*)&wlds[ct][ks][lane][0] = make_uint4(u0, u1, u2, u3);
    }
    __syncthreads();

    const int w = tid >> 6;
    const int lane = tid & 63;
    const int row = blockIdx.x * 128 + w * 32 + (lane & 31);
    const int rclamp = (row < nrows) ? row : 0;
    const float* xrow = x + (size_t)rclamp * FEAT + 8 * (lane >> 5);

    f32x16 acc0 = {0}, acc1 = {0}, acc2 = {0}, acc3 = {0};

#pragma unroll
    for (int ks = 0; ks < 8; ks++) {
        float4 f0 = *(const float4*)&xrow[ks * 16];
        float4 f1 = *(const float4*)&xrow[ks * 16 + 4];
        union { uint4 u; short8 s; } a;
        a.u = make_uint4(pkbf(f0.x, f0.y), pkbf(f0.z, f0.w), pkbf(f1.x, f1.y), pkbf(f1.z, f1.w));
        union { uint4 u; short8 s; } b0, b1, b2, b3;
        b0.u = *(const uint4*)&wlds[0][ks][lane][0];
        b1.u = *(const uint4*)&wlds[1][ks][lane][0];
        b2.u = *(const uint4*)&wlds[2][ks][lane][0];
        b3.u = *(const uint4*)&wlds[3][ks][lane][0];
        acc0 = __builtin_amdgcn_mfma_f32_32x32x16_bf16(a.s, b0.s, acc0, 0, 0, 0);
        acc1 = __builtin_amdgcn_mfma_f32_32x32x16_bf16(a.s, b1.s, acc1, 0, 0, 0);
        acc2 = __builtin_amdgcn_mfma_f32_32x32x16_bf16(a.s, b2.s, acc2, 0, 0, 0);
        acc3 = __builtin_amdgcn_mfma_f32_32x32x16_bf16(a.s, b3.s, acc3, 0, 0, 0);
    }

    const int rb = blockIdx.x * 128 + w * 32 + 4 * (lane >> 5);
    const int cb = lane & 31;
#pragma unroll
    for (int r = 0; r < 16; r++) {
        int rr = rb + (r & 3) + 8 * (r >> 2);
        if (rr < nrows) {
            unsigned short* p = hb + (size_t)rr * FEAT + cb;
            p[0]  = bf16of(acc0[r]);
            p[32] = bf16of(acc1[r]);
            p[64] = bf16of(acc2[r]);
            p[96] = bf16of(acc3[r]);
        }
    }
}

// ---------------------------------------------------------------------------
// Kernel G: aggregate — one wave per node, 2 cols/lane (one bf16x2 word),
// 8 gathers in flight. out[c] = ELU( sum h[r]*nrm + h[c]*dc^2 + b )
// ---------------------------------------------------------------------------
__global__ __launch_bounds__(256) void k_agg(const int* __restrict__ start,
                                             const int2* __restrict__ rec, const float* __restrict__ dinv,
                                             const unsigned* __restrict__ hb, const float* __restrict__ b,
                                             float* __restrict__ out, int n) {
    int wave = (blockIdx.x * 256 + threadIdx.x) >> 6;
    int lane = threadIdx.x & 63;
    if (wave >= n) return;
    const int c = wave;
    const int j0 = lane * 2;
    const int s0 = start[c];
    const int m = start[c + 1] - s0;
    const float dc = dinv[c];

    float2 hv = upbf(hb[(size_t)c * 64 + lane]);
    float ax = hv.x * dc * dc + b[j0];
    float ay = hv.y * dc * dc + b[j0 + 1];

    int k = 0;
    for (; k + 7 < m; k += 8) {
        int2 r[8];
        unsigned g[8];
#pragma unroll
        for (int u = 0; u < 8; u++) r[u] = rec[s0 + k + u];
#pragma unroll
        for (int u = 0; u < 8; u++) g[u] = hb[(size_t)r[u].x * 64 + lane];
#pragma unroll
        for (int u = 0; u < 8; u++) {
            float w = __int_as_float(r[u].y) * dc;
            float2 v = upbf(g[u]);
            ax += v.x * w;
            ay += v.y * w;
        }
    }
    for (; k + 3 < m; k += 4) {
        int2 r[4];
        unsigned g[4];
#pragma unroll
        for (int u = 0; u < 4; u++) r[u] = rec[s0 + k + u];
#pragma unroll
        for (int u = 0; u < 4; u++) g[u] = hb[(size_t)r[u].x * 64 + lane];
#pragma unroll
        for (int u = 0; u < 4; u++) {
            float w = __int_as_float(r[u].y) * dc;
            float2 v = upbf(g[u]);
            ax += v.x * w;
            ay += v.y * w;
        }
    }
    for (; k < m; k++) {
        int2 r0 = rec[s0 + k];
        float w = __int_as_float(r0.y) * dc;
        float2 v = upbf(hb[(size_t)r0.x * 64 + lane]);
        ax += v.x * w;
        ay += v.y * w;
    }

    ax = (ax > 0.0f) ? ax : expm1f(ax);
    ay = (ay > 0.0f) ? ay : expm1f(ay);
    *(float2*)&out[(size_t)c * FEAT + j0] = make_float2(ax, ay);
}

// ---------------------------------------------------------------------------
// Kernel H: BN partial stats over out (read-only pass)
// ---------------------------------------------------------------------------
__global__ __launch_bounds__(256) void k_bnstat(const float* __restrict__ out,
                                                float* __restrict__ bnsum, float* __restrict__ bnsq,
                                                int n, int rows_per_block) {
    int j = threadIdx.x & 127;
    int half = threadIdx.x >> 7;
    int r0 = blockIdx.x * rows_per_block;
    int r1 = r0 + rows_per_block; if (r1 > n) r1 = n;
    float s = 0.0f, ss = 0.0f;
    for (int r = r0 + half; r < r1; r += 2) {
        float v = out[(size_t)r * FEAT + j];
        s += v; ss += v * v;
    }
    atomicAdd(&bnsum[j], s);
    atomicAdd(&bnsq[j], ss);
}

// ---------------------------------------------------------------------------
// Kernel I: BN finalize — bnsum <- mu, bnsq <- rsqrt(var+eps)
// ---------------------------------------------------------------------------
__global__ void k_bn_finalize(float* __restrict__ bnsum, float* __restrict__ bnsq, float n) {
    int j = threadIdx.x;
    float mu = bnsum[j] / n;
    float var = bnsq[j] / n - mu * mu;
    if (var < 0.0f) var = 0.0f;
    bnsum[j] = mu;
    bnsq[j] = rsqrtf(var + 1e-5f);
}

// ---------------------------------------------------------------------------
// Kernel J: BN apply + LayerNorm, one wave per row, 2 cols per lane
// ---------------------------------------------------------------------------
__global__ __launch_bounds__(256) void k_bn_ln(float* __restrict__ out, const float* __restrict__ mu,
                                               const float* __restrict__ rsig,
                                               const float* __restrict__ bng, const float* __restrict__ bnb,
                                               const float* __restrict__ lng, const float* __restrict__ lnb,
                                               int n) {
    int wave = (blockIdx.x * 256 + threadIdx.x) >> 6;
    int lane = threadIdx.x & 63;
    if (wave >= n) return;
    int j0 = lane * 2;
    float2 v = *(const float2*)&out[(size_t)wave * FEAT + j0];
    float t0 = (v.x - mu[j0])     * rsig[j0]     * bng[j0]     + bnb[j0];
    float t1 = (v.y - mu[j0 + 1]) * rsig[j0 + 1] * bng[j0 + 1] + bnb[j0 + 1];
    float s = t0 + t1;
    float ss = t0 * t0 + t1 * t1;
#pragma unroll
    for (int o = 32; o; o >>= 1) {
        s  += __shfl_xor(s, o);
        ss += __shfl_xor(ss, o);
    }
    float m = s * (1.0f / FEAT);
    float var = ss * (1.0f / FEAT) - m * m;
    float r = rsqrtf(var + 1e-5f);
    float o0 = (t0 - m) * r * lng[j0]     + lnb[j0];
    float o1 = (t1 - m) * r * lng[j0 + 1] + lnb[j0 + 1];
    *(float2*)&out[(size_t)wave * FEAT + j0] = make_float2(o0, o1);
}

// ---------------------------------------------------------------------------
extern "C" void kernel_launch(void* const* d_in, const int* in_sizes, int n_in,
                              void* d_out, int out_size, void* d_ws, size_t ws_size,
                              hipStream_t stream) {
    const float* x   = (const float*)d_in[0];
    const int*   ei  = (const int*)  d_in[1];
    const float* ew  = (const float*)d_in[2];
    const float* W   = (const float*)d_in[3];
    const float* b   = (const float*)d_in[4];
    const float* bng = (const float*)d_in[5];
    const float* bnb = (const float*)d_in[6];
    const float* lng = (const float*)d_in[7];
    const float* lnb = (const float*)d_in[8];

    const int N = in_sizes[0] / FEAT;     // 50000
    const int E = in_sizes[2];            // 800000
    const int NB = (N + 1023) / 1024;     // scan blocks

    float* out = (float*)d_out;

    // workspace layout (16B-aligned segments):
    //   hb [N*64] u32 (bf16x2, 12.8MB) | rec [E] int2 | packed [N] u64 |
    //   dinv [N] f32 | rank [E] i32 | start [N+4] i32 | bsum [NB] i32 |
    //   bnsum/bnsq [128] f32
    unsigned*           hb     = (unsigned*)d_ws;
    int2*               rec    = (int2*)(hb + (size_t)N * 64);
    unsigned long long* packed = (unsigned long long*)(rec + E);
    float*              dinv   = (float*)(packed + N);
    int*                rank   = (int*)(dinv + N);
    int*                start  = rank + E;
    int*                bsum   = start + N + 4;
    float*              bnsum  = (float*)(bsum + NB);
    float*              bnsq   = bnsum + FEAT;

    // A: init
    k_init<<<(N + 255) / 256, 256, 0, stream>>>(packed, bnsum, bnsq, N);
    // B: packed histogram (1 atomic/edge) + rank capture
    k_hist<<<(E + 255) / 256, 256, 0, stream>>>(ei, ew, packed, rank, E);
    // Scan phase 1/2/3 (+fused dinv in phase 3)
    k_scan_local<<<NB, 256, 0, stream>>>(packed, start, bsum, N);
    k_scan_bsum<<<1, 64, 0, stream>>>(bsum, NB);
    k_scan_add<<<NB, 256, 0, stream>>>(start, bsum, packed, dinv, N, E);
    // F: h = x @ W (MFMA, bf16 out)
    k_gemm_mfma<<<(N + 127) / 128, 256, 0, stream>>>(x, W, (unsigned short*)hb, N);
    // E: fill CSR records (no atomics)
    k_fill<<<(E + 255) / 256, 256, 0, stream>>>(ei, ew, dinv, start, rank, rec, E);
    // G: aggregate + self-loop + bias + ELU (no atomics)
    k_agg<<<((N * 64) + 255) / 256, 256, 0, stream>>>(start, rec, dinv, hb, b, out, N);
    // H: BN partial stats
    {
        int rows_per_block = 100;
        int blocks = (N + rows_per_block - 1) / rows_per_block;
        k_bnstat<<<blocks, 256, 0, stream>>>(out, bnsum, bnsq, N, rows_per_block);
    }
    // I: BN finalize
    k_bn_finalize<<<1, FEAT, 0, stream>>>(bnsum, bnsq, (float)N);
    // J: BN apply + LayerNorm
    k_bn_ln<<<(N + 3) / 4, 256, 0, stream>>>(out, bnsum, bnsq, bng, bnb, lng, lnb, N);
}

// Round 7
// 138.642 us; speedup vs baseline: 3.6610x; 1.3017x over previous
//
#include <hip/hip_runtime.h>
#include <math.h>

#define FEAT 128
#define FXS 16777216.0f          // 2^24 fixed-point scale for edge weights
#define FXI (1.0f / 16777216.0f)
#define AGG_BLOCKS 2048          // k_agg grid (8 blocks/CU); also BN partial rows

typedef __attribute__((ext_vector_type(8)))  short short8;
typedef __attribute__((ext_vector_type(16))) float f32x16;

// bf16 helpers (bit-level, RNE pack / exact unpack)
__device__ inline unsigned pkbf(float a, float b) {
    unsigned ua = __float_as_uint(a), ub = __float_as_uint(b);
    ua += 0x7fffu + ((ua >> 16) & 1u);
    ub += 0x7fffu + ((ub >> 16) & 1u);
    return (ua >> 16) | (ub & 0xffff0000u);
}
__device__ inline unsigned short bf16of(float a) {
    unsigned ua = __float_as_uint(a);
    ua += 0x7fffu + ((ua >> 16) & 1u);
    return (unsigned short)(ua >> 16);
}
__device__ inline float2 upbf(unsigned v) {
    return make_float2(__uint_as_float(v << 16), __uint_as_float(v & 0xffff0000u));
}

// ---------------------------------------------------------------------------
// Kernel A: init — packed = {cnt=0, deg=fx(1.0)} (self-loop), BN sums=0
// ---------------------------------------------------------------------------
__global__ __launch_bounds__(256) void k_init(unsigned long long* __restrict__ packed,
                                              float* __restrict__ bnsum, float* __restrict__ bnsq,
                                              int n) {
    int i = blockIdx.x * 256 + threadIdx.x;
    if (i < n) packed[i] = 16777216ULL;   // fx(1.0), count 0
    if (i < FEAT) { bnsum[i] = 0.0f; bnsq[i] = 0.0f; }
}

// ---------------------------------------------------------------------------
// Kernel B: histogram — ONE 64-bit atomic per edge; old>>32 = rank in bucket
// ---------------------------------------------------------------------------
__global__ __launch_bounds__(256) void k_hist(const int* __restrict__ ei, const float* __restrict__ ew,
                                              unsigned long long* __restrict__ packed,
                                              int* __restrict__ rank, int E) {
    int e = blockIdx.x * 256 + threadIdx.x;
    if (e < E) {
        int c = ei[E + e];
        unsigned fx = (unsigned)(ew[e] * FXS + 0.5f);
        unsigned long long old = atomicAdd(&packed[c], (1ULL << 32) | (unsigned long long)fx);
        rank[e] = (int)(old >> 32);
    }
}

// ---------------------------------------------------------------------------
// 3-phase parallel exclusive scan of counts (1024 elems/block, 4/thread)
// ---------------------------------------------------------------------------
__global__ __launch_bounds__(256) void k_scan_local(const unsigned long long* __restrict__ packed,
                                                    int* __restrict__ start, int* __restrict__ bsum, int n) {
    __shared__ int wtot[4];
    const int tid = threadIdx.x;
    const int i0 = blockIdx.x * 1024 + tid * 4;
    int4 v = make_int4(0, 0, 0, 0);
    if (i0 + 3 < n) {
        ulonglong2 p0 = *(const ulonglong2*)&packed[i0];
        ulonglong2 p1 = *(const ulonglong2*)&packed[i0 + 2];
        v = make_int4((int)(p0.x >> 32), (int)(p0.y >> 32), (int)(p1.x >> 32), (int)(p1.y >> 32));
    } else if (i0 < n) {
        v.x = (int)(packed[i0] >> 32);
        if (i0 + 1 < n) v.y = (int)(packed[i0 + 1] >> 32);
        if (i0 + 2 < n) v.z = (int)(packed[i0 + 2] >> 32);
    }
    const int t = v.x + v.y + v.z + v.w;
    const int lane = tid & 63;
    const int wave = tid >> 6;
    int s = t;
#pragma unroll
    for (int o = 1; o < 64; o <<= 1) {
        int u = __shfl_up(s, o);
        if (lane >= o) s += u;
    }
    if (lane == 63) wtot[wave] = s;
    __syncthreads();
    int woff = 0;
#pragma unroll
    for (int w = 0; w < 4; w++) if (w < wave) woff += wtot[w];
    const int excl = woff + s - t;
    int4 o4 = make_int4(excl, excl + v.x, excl + v.x + v.y, excl + v.x + v.y + v.z);
    if (i0 + 3 < n) *(int4*)&start[i0] = o4;
    else if (i0 < n) {
        start[i0] = o4.x;
        if (i0 + 1 < n) start[i0 + 1] = o4.y;
        if (i0 + 2 < n) start[i0 + 2] = o4.z;
    }
    if (tid == 0) bsum[blockIdx.x] = 0;
    __syncthreads();
    if (tid == 255) bsum[blockIdx.x] = wtot[0] + wtot[1] + wtot[2] + wtot[3];
}

__global__ __launch_bounds__(64) void k_scan_bsum(int* __restrict__ bsum, int nb) {
    const int lane = threadIdx.x;
    int carry = 0;
    for (int base = 0; base < nb; base += 64) {
        int i = base + lane;
        int v = (i < nb) ? bsum[i] : 0;
        int s = v;
#pragma unroll
        for (int o = 1; o < 64; o <<= 1) {
            int u = __shfl_up(s, o);
            if (lane >= o) s += u;
        }
        if (i < nb) bsum[i] = carry + s - v;
        carry += __shfl(s, 63);
    }
}

__global__ __launch_bounds__(256) void k_scan_add(int* __restrict__ start, const int* __restrict__ bsum,
                                                  const unsigned long long* __restrict__ packed,
                                                  float* __restrict__ dinv, int n, int E) {
    const int i0 = blockIdx.x * 1024 + threadIdx.x * 4;
    const int off = bsum[blockIdx.x];
    if (i0 == 0) start[n] = E;
    if (i0 + 3 < n) {
        int4 s4 = *(int4*)&start[i0];
        s4.x += off; s4.y += off; s4.z += off; s4.w += off;
        *(int4*)&start[i0] = s4;
        ulonglong2 p0 = *(const ulonglong2*)&packed[i0];
        ulonglong2 p1 = *(const ulonglong2*)&packed[i0 + 2];
        float4 d4;
        d4.x = rsqrtf((float)(unsigned)(p0.x & 0xffffffffULL) * FXI);
        d4.y = rsqrtf((float)(unsigned)(p0.y & 0xffffffffULL) * FXI);
        d4.z = rsqrtf((float)(unsigned)(p1.x & 0xffffffffULL) * FXI);
        d4.w = rsqrtf((float)(unsigned)(p1.y & 0xffffffffULL) * FXI);
        *(float4*)&dinv[i0] = d4;
    } else {
        for (int i = i0; i < n && i < i0 + 4; i++) {
            start[i] += off;
            dinv[i] = rsqrtf((float)(unsigned)(packed[i] & 0xffffffffULL) * FXI);
        }
    }
}

// ---------------------------------------------------------------------------
// Kernel E: fill edge records grouped by target — NO atomics (slot from rank)
// ---------------------------------------------------------------------------
__global__ __launch_bounds__(256) void k_fill(const int* __restrict__ ei, const float* __restrict__ ew,
                                              const float* __restrict__ dinv, const int* __restrict__ start,
                                              const int* __restrict__ rank, int2* __restrict__ rec, int E) {
    int e = blockIdx.x * 256 + threadIdx.x;
    if (e < E) {
        int r = ei[e];
        int c = ei[E + e];
        rec[start[c] + rank[e]] = make_int2(r, __float_as_int(ew[e] * dinv[r]));
    }
}

// ---------------------------------------------------------------------------
// Kernel F: h = x @ W via MFMA 32x32x16 bf16. (unchanged from R6)
// ---------------------------------------------------------------------------
__global__ __launch_bounds__(256) void k_gemm_mfma(const float* __restrict__ x,
                                                   const float* __restrict__ Wg,
                                                   unsigned short* __restrict__ hb, int nrows) {
    __shared__ unsigned wlds[4][8][64][4];   // 32 KB
    const int tid = threadIdx.x;

    for (int idx = tid; idx < 4 * 8 * 64; idx += 256) {
        int lane = idx & 63;
        int ks = (idx >> 6) & 7;
        int ct = idx >> 9;
        int krow = ks * 16 + 8 * (lane >> 5);
        int col = ct * 32 + (lane & 31);
        unsigned u0 = pkbf(Wg[(krow + 0) * FEAT + col], Wg[(krow + 1) * FEAT + col]);
        unsigned u1 = pkbf(Wg[(krow + 2) * FEAT + col], Wg[(krow + 3) * FEAT + col]);
        unsigned u2 = pkbf(Wg[(krow + 4) * FEAT + col], Wg[(krow + 5) * FEAT + col]);
        unsigned u3 = pkbf(Wg[(krow + 6) * FEAT + col], Wg[(krow + 7) * FEAT + col]);
        *(uint4*)&wlds[ct][ks][lane][0] = make_uint4(u0, u1, u2, u3);
    }
    __syncthreads();

    const int w = tid >> 6;
    const int lane = tid & 63;
    const int row = blockIdx.x * 128 + w * 32 + (lane & 31);
    const int rclamp = (row < nrows) ? row : 0;
    const float* xrow = x + (size_t)rclamp * FEAT + 8 * (lane >> 5);

    f32x16 acc0 = {0}, acc1 = {0}, acc2 = {0}, acc3 = {0};

#pragma unroll
    for (int ks = 0; ks < 8; ks++) {
        float4 f0 = *(const float4*)&xrow[ks * 16];
        float4 f1 = *(const float4*)&xrow[ks * 16 + 4];
        union { uint4 u; short8 s; } a;
        a.u = make_uint4(pkbf(f0.x, f0.y), pkbf(f0.z, f0.w), pkbf(f1.x, f1.y), pkbf(f1.z, f1.w));
        union { uint4 u; short8 s; } b0, b1, b2, b3;
        b0.u = *(const uint4*)&wlds[0][ks][lane][0];
        b1.u = *(const uint4*)&wlds[1][ks][lane][0];
        b2.u = *(const uint4*)&wlds[2][ks][lane][0];
        b3.u = *(const uint4*)&wlds[3][ks][lane][0];
        acc0 = __builtin_amdgcn_mfma_f32_32x32x16_bf16(a.s, b0.s, acc0, 0, 0, 0);
        acc1 = __builtin_amdgcn_mfma_f32_32x32x16_bf16(a.s, b1.s, acc1, 0, 0, 0);
        acc2 = __builtin_amdgcn_mfma_f32_32x32x16_bf16(a.s, b2.s, acc2, 0, 0, 0);
        acc3 = __builtin_amdgcn_mfma_f32_32x32x16_bf16(a.s, b3.s, acc3, 0, 0, 0);
    }

    const int rb = blockIdx.x * 128 + w * 32 + 4 * (lane >> 5);
    const int cb = lane & 31;
#pragma unroll
    for (int r = 0; r < 16; r++) {
        int rr = rb + (r & 3) + 8 * (r >> 2);
        if (rr < nrows) {
            unsigned short* p = hb + (size_t)rr * FEAT + cb;
            p[0]  = bf16of(acc0[r]);
            p[32] = bf16of(acc1[r]);
            p[64] = bf16of(acc2[r]);
            p[96] = bf16of(acc3[r]);
        }
    }
}

// ---------------------------------------------------------------------------
// Kernel G: aggregate + FUSED BN partial stats.
// Grid-stride over nodes: wave wg handles c = wg, wg+4*G, ...
// Per-thread (s,ss) for its 2 cols accumulated across nodes; block-end LDS
// reduce across the 4 waves -> per-block partial rows ps/pss[blockIdx][128].
// ---------------------------------------------------------------------------
__global__ __launch_bounds__(256) void k_agg(const int* __restrict__ start,
                                             const int2* __restrict__ rec, const float* __restrict__ dinv,
                                             const unsigned* __restrict__ hb, const float* __restrict__ b,
                                             float* __restrict__ out,
                                             float* __restrict__ ps, float* __restrict__ pss, int n) {
    const int tid = threadIdx.x;
    const int lane = tid & 63;
    const int wv = tid >> 6;
    const int j0 = lane * 2;
    const float bx = b[j0];
    const float by = b[j0 + 1];

    float sx = 0.0f, ssx = 0.0f, sy = 0.0f, ssy = 0.0f;

    for (int c = blockIdx.x * 4 + wv; c < n; c += AGG_BLOCKS * 4) {
        const int s0 = start[c];
        const int m = start[c + 1] - s0;
        const float dc = dinv[c];

        float2 hv = upbf(hb[(size_t)c * 64 + lane]);
        float ax = hv.x * dc * dc + bx;
        float ay = hv.y * dc * dc + by;

        int k = 0;
        for (; k + 7 < m; k += 8) {
            int2 r[8];
            unsigned g[8];
#pragma unroll
            for (int u = 0; u < 8; u++) r[u] = rec[s0 + k + u];
#pragma unroll
            for (int u = 0; u < 8; u++) g[u] = hb[(size_t)r[u].x * 64 + lane];
#pragma unroll
            for (int u = 0; u < 8; u++) {
                float w = __int_as_float(r[u].y) * dc;
                float2 v = upbf(g[u]);
                ax += v.x * w;
                ay += v.y * w;
            }
        }
        for (; k + 3 < m; k += 4) {
            int2 r[4];
            unsigned g[4];
#pragma unroll
            for (int u = 0; u < 4; u++) r[u] = rec[s0 + k + u];
#pragma unroll
            for (int u = 0; u < 4; u++) g[u] = hb[(size_t)r[u].x * 64 + lane];
#pragma unroll
            for (int u = 0; u < 4; u++) {
                float w = __int_as_float(r[u].y) * dc;
                float2 v = upbf(g[u]);
                ax += v.x * w;
                ay += v.y * w;
            }
        }
        for (; k < m; k++) {
            int2 r0 = rec[s0 + k];
            float w = __int_as_float(r0.y) * dc;
            float2 v = upbf(hb[(size_t)r0.x * 64 + lane]);
            ax += v.x * w;
            ay += v.y * w;
        }

        ax = (ax > 0.0f) ? ax : expm1f(ax);
        ay = (ay > 0.0f) ? ay : expm1f(ay);
        *(float2*)&out[(size_t)c * FEAT + j0] = make_float2(ax, ay);

        sx += ax; ssx += ax * ax;
        sy += ay; ssy += ay * ay;
    }

    // block reduce across the 4 waves (same lane = same column pair)
    __shared__ float4 sh[256];
    sh[tid] = make_float4(sx, sy, ssx, ssy);
    __syncthreads();
    if (tid < 64) {
        float4 a0 = sh[tid], a1 = sh[tid + 64], a2 = sh[tid + 128], a3 = sh[tid + 192];
        float4 t;
        t.x = a0.x + a1.x + a2.x + a3.x;
        t.y = a0.y + a1.y + a2.y + a3.y;
        t.z = a0.z + a1.z + a2.z + a3.z;
        t.w = a0.w + a1.w + a2.w + a3.w;
        *(float2*)&ps[(size_t)blockIdx.x * FEAT + 2 * tid]  = make_float2(t.x, t.y);
        *(float2*)&pss[(size_t)blockIdx.x * FEAT + 2 * tid] = make_float2(t.z, t.w);
    }
}

// ---------------------------------------------------------------------------
// Kernel H: reduce per-block BN partials -> bnsum/bnsq (64 blocks, 32 rows ea)
// ---------------------------------------------------------------------------
__global__ __launch_bounds__(256) void k_bnreduce(const float* __restrict__ ps,
                                                  const float* __restrict__ pss,
                                                  float* __restrict__ bnsum, float* __restrict__ bnsq) {
    const int col = threadIdx.x & 127;
    const int half = threadIdx.x >> 7;
    const float* src = half ? pss : ps;
    const int rows = AGG_BLOCKS / 64;
    const int r0 = blockIdx.x * rows;
    float acc = 0.0f;
    for (int r = r0; r < r0 + rows; r++) acc += src[(size_t)r * FEAT + col];
    atomicAdd(half ? &bnsq[col] : &bnsum[col], acc);
}

// ---------------------------------------------------------------------------
// Kernel I: BN finalize — bnsum <- mu, bnsq <- rsqrt(var+eps)
// ---------------------------------------------------------------------------
__global__ void k_bn_finalize(float* __restrict__ bnsum, float* __restrict__ bnsq, float n) {
    int j = threadIdx.x;
    float mu = bnsum[j] / n;
    float var = bnsq[j] / n - mu * mu;
    if (var < 0.0f) var = 0.0f;
    bnsum[j] = mu;
    bnsq[j] = rsqrtf(var + 1e-5f);
}

// ---------------------------------------------------------------------------
// Kernel J: BN apply + LayerNorm, one wave per row, 2 cols per lane
// ---------------------------------------------------------------------------
__global__ __launch_bounds__(256) void k_bn_ln(float* __restrict__ out, const float* __restrict__ mu,
                                               const float* __restrict__ rsig,
                                               const float* __restrict__ bng, const float* __restrict__ bnb,
                                               const float* __restrict__ lng, const float* __restrict__ lnb,
                                               int n) {
    int wave = (blockIdx.x * 256 + threadIdx.x) >> 6;
    int lane = threadIdx.x & 63;
    if (wave >= n) return;
    int j0 = lane * 2;
    float2 v = *(const float2*)&out[(size_t)wave * FEAT + j0];
    float t0 = (v.x - mu[j0])     * rsig[j0]     * bng[j0]     + bnb[j0];
    float t1 = (v.y - mu[j0 + 1]) * rsig[j0 + 1] * bng[j0 + 1] + bnb[j0 + 1];
    float s = t0 + t1;
    float ss = t0 * t0 + t1 * t1;
#pragma unroll
    for (int o = 32; o; o >>= 1) {
        s  += __shfl_xor(s, o);
        ss += __shfl_xor(ss, o);
    }
    float m = s * (1.0f / FEAT);
    float var = ss * (1.0f / FEAT) - m * m;
    float r = rsqrtf(var + 1e-5f);
    float o0 = (t0 - m) * r * lng[j0]     + lnb[j0];
    float o1 = (t1 - m) * r * lng[j0 + 1] + lnb[j0 + 1];
    *(float2*)&out[(size_t)wave * FEAT + j0] = make_float2(o0, o1);
}

// ---------------------------------------------------------------------------
extern "C" void kernel_launch(void* const* d_in, const int* in_sizes, int n_in,
                              void* d_out, int out_size, void* d_ws, size_t ws_size,
                              hipStream_t stream) {
    const float* x   = (const float*)d_in[0];
    const int*   ei  = (const int*)  d_in[1];
    const float* ew  = (const float*)d_in[2];
    const float* W   = (const float*)d_in[3];
    const float* b   = (const float*)d_in[4];
    const float* bng = (const float*)d_in[5];
    const float* bnb = (const float*)d_in[6];
    const float* lng = (const float*)d_in[7];
    const float* lnb = (const float*)d_in[8];

    const int N = in_sizes[0] / FEAT;     // 50000
    const int E = in_sizes[2];            // 800000
    const int NB = (N + 1023) / 1024;     // scan blocks

    float* out = (float*)d_out;

    // workspace layout (16B-aligned segments):
    //   hb [N*64] u32 (bf16x2, 12.8MB) | rec [E] int2 (6.4MB) | packed [N] u64 |
    //   dinv [N] f32 | rank [E] i32 (3.2MB) | start [N+4] i32 | bsum [NB] i32 |
    //   bnsum/bnsq [128] f32 | ps/pss [AGG_BLOCKS*128] f32 (2MB)
    unsigned*           hb     = (unsigned*)d_ws;
    int2*               rec    = (int2*)(hb + (size_t)N * 64);
    unsigned long long* packed = (unsigned long long*)(rec + E);
    float*              dinv   = (float*)(packed + N);
    int*                rank   = (int*)(dinv + N);
    int*                start  = rank + E;
    int*                bsum   = start + N + 4;
    float*              bnsum  = (float*)(bsum + NB);
    float*              bnsq   = bnsum + FEAT;
    float*              ps     = bnsq + FEAT;
    float*              pss    = ps + (size_t)AGG_BLOCKS * FEAT;

    // A: init
    k_init<<<(N + 255) / 256, 256, 0, stream>>>(packed, bnsum, bnsq, N);
    // B: packed histogram (1 atomic/edge) + rank capture
    k_hist<<<(E + 255) / 256, 256, 0, stream>>>(ei, ew, packed, rank, E);
    // Scan phase 1/2/3 (+fused dinv in phase 3)
    k_scan_local<<<NB, 256, 0, stream>>>(packed, start, bsum, N);
    k_scan_bsum<<<1, 64, 0, stream>>>(bsum, NB);
    k_scan_add<<<NB, 256, 0, stream>>>(start, bsum, packed, dinv, N, E);
    // F: h = x @ W (MFMA, bf16 out)
    k_gemm_mfma<<<(N + 127) / 128, 256, 0, stream>>>(x, W, (unsigned short*)hb, N);
    // E: fill CSR records (no atomics)
    k_fill<<<(E + 255) / 256, 256, 0, stream>>>(ei, ew, dinv, start, rank, rec, E);
    // G: aggregate + self-loop + bias + ELU + fused BN partials
    k_agg<<<AGG_BLOCKS, 256, 0, stream>>>(start, rec, dinv, hb, b, out, ps, pss, N);
    // H: reduce BN partials
    k_bnreduce<<<64, 256, 0, stream>>>(ps, pss, bnsum, bnsq);
    // I: BN finalize
    k_bn_finalize<<<1, FEAT, 0, stream>>>(bnsum, bnsq, (float)N);
    // J: BN apply + LayerNorm
    k_bn_ln<<<(N + 3) / 4, 256, 0, stream>>>(out, bnsum, bnsq, bng, bnb, lng, lnb, N);
}

// Round 8
// 123.483 us; speedup vs baseline: 4.1104x; 1.1228x over previous
//
#include <hip/hip_runtime.h>
#include <math.h>

#define FEAT 128
#define FXS 16777216.0f          // 2^24 fixed-point scale for edge weights
#define FXI (1.0f / 16777216.0f)
#define AGG_BLOCKS 2048          // k_agg grid; also BN partial rows
#define NPB 256                  // nodes per bucket (bucket = c >> 8)
#define EPBA 4096                // edges per phase-A block

typedef __attribute__((ext_vector_type(8)))  short short8;
typedef __attribute__((ext_vector_type(16))) float f32x16;

// bf16 helpers (bit-level, RNE pack / exact unpack)
__device__ inline unsigned pkbf(float a, float b) {
    unsigned ua = __float_as_uint(a), ub = __float_as_uint(b);
    ua += 0x7fffu + ((ua >> 16) & 1u);
    ub += 0x7fffu + ((ub >> 16) & 1u);
    return (ua >> 16) | (ub & 0xffff0000u);
}
__device__ inline unsigned short bf16of(float a) {
    unsigned ua = __float_as_uint(a);
    ua += 0x7fffu + ((ua >> 16) & 1u);
    return (unsigned short)(ua >> 16);
}
__device__ inline float2 upbf(unsigned v) {
    return make_float2(__uint_as_float(v << 16), __uint_as_float(v & 0xffff0000u));
}

// ---------------------------------------------------------------------------
// Kernel A: init — bucket cursors to region bases, BN sums=0, start[n]=E
// ---------------------------------------------------------------------------
__global__ __launch_bounds__(256) void k_init2(unsigned* __restrict__ gcur,
                                               float* __restrict__ bnsum, float* __restrict__ bnsq,
                                               int* __restrict__ start,
                                               int nbuk, int cap, int n, int E) {
    int i = threadIdx.x;
    if (i < nbuk) gcur[i] = (unsigned)(i * cap);
    if (i < FEAT) { bnsum[i] = 0.0f; bnsq[i] = 0.0f; }
    if (i == 0) start[n] = E;
}

// ---------------------------------------------------------------------------
// Kernel B (phase A): bucket-partition edges. LDS histogram over nbuk coarse
// buckets, one global atomic per (block,bucket) to reserve, LDS-cursor scatter.
// Record: u64 = r | c<<17 | fx24(ew)<<34
// ---------------------------------------------------------------------------
__global__ __launch_bounds__(256) void k_bucket(const int* __restrict__ ei, const float* __restrict__ ew,
                                                unsigned long long* __restrict__ buk,
                                                unsigned* __restrict__ gcur,
                                                int E, int nbuk, int cap) {
    __shared__ unsigned bcnt[256];
    __shared__ unsigned bbase[256];
    const int tid = threadIdx.x;
    for (int i = tid; i < nbuk; i += 256) bcnt[i] = 0;
    __syncthreads();
    const int e0 = blockIdx.x * EPBA;
    const int e1 = (e0 + EPBA < E) ? e0 + EPBA : E;
    for (int e = e0 + tid; e < e1; e += 256) {
        int c = ei[E + e];
        atomicAdd(&bcnt[c >> 8], 1u);
    }
    __syncthreads();
    for (int i = tid; i < nbuk; i += 256) {
        unsigned nn = bcnt[i];
        bbase[i] = nn ? atomicAdd(&gcur[i], nn) : 0u;
        bcnt[i] = 0;   // reuse as local cursor
    }
    __syncthreads();
    for (int e = e0 + tid; e < e1; e += 256) {
        int r = ei[e];
        int c = ei[E + e];
        unsigned fx = (unsigned)(ew[e] * FXS + 0.5f);
        int b = c >> 8;
        unsigned slot = bbase[b] + atomicAdd(&bcnt[b], 1u);
        buk[slot] = (unsigned long long)(unsigned)r
                  | ((unsigned long long)(unsigned)c << 17)
                  | ((unsigned long long)fx << 34);
    }
}

// ---------------------------------------------------------------------------
// Kernel C (phase B): per-bucket CSR build. One block per bucket.
// pass1: LDS u64 atomic {cnt<<40 | deg_fx} per edge; scan counts -> start/dinv;
// pass2: LDS-cursor scatter to final rec = (r, ew_raw).
// ---------------------------------------------------------------------------
__global__ __launch_bounds__(256) void k_csr(const unsigned long long* __restrict__ buk,
                                             const unsigned* __restrict__ gcur,
                                             int2* __restrict__ rec, int* __restrict__ start,
                                             float* __restrict__ dinv,
                                             int n, int nbuk, int cap) {
    __shared__ unsigned long long cd[NPB];
    __shared__ unsigned curL[NPB];
    __shared__ unsigned sizeL[256];
    __shared__ unsigned wt[4];
    const int b = blockIdx.x;
    const int tid = threadIdx.x;
    const int lane = tid & 63;
    const int wv = tid >> 6;

    // bucket sizes + exclusive prefix -> global CSR base of this bucket
    unsigned sz = (tid < nbuk) ? (gcur[tid] - (unsigned)(tid * cap)) : 0u;
    {
        unsigned s = sz;
#pragma unroll
        for (int o = 1; o < 64; o <<= 1) {
            unsigned u = __shfl_up((int)s, o);
            if (lane >= o) s += u;
        }
        if (lane == 63) wt[wv] = s;
        __syncthreads();
        unsigned woff = 0;
#pragma unroll
        for (int w = 0; w < 4; w++) if (w < wv) woff += wt[w];
        sizeL[tid] = woff + s - sz;   // exclusive
        __syncthreads();
    }
    const unsigned bukStartG = sizeL[b];
    const unsigned mySize = gcur[b] - (unsigned)(b * cap);
    const unsigned base = (unsigned)b * (unsigned)cap;

    cd[tid] = 0ULL;
    __syncthreads();

    // pass1: count + weighted degree (fixed point), one LDS u64 atomic/edge
    for (unsigned i = tid; i < mySize; i += 256) {
        unsigned long long v = buk[base + i];
        unsigned ci = ((unsigned)(v >> 17)) & 255u;
        atomicAdd(&cd[ci], (1ULL << 40) | (v >> 34));
    }
    __syncthreads();

    // scan counts, write start/dinv, init cursors
    {
        unsigned long long v = cd[tid];
        unsigned cnt = (unsigned)(v >> 40);
        float deg = 1.0f + (float)(v & ((1ULL << 40) - 1ULL)) * FXI;
        unsigned s = cnt;
#pragma unroll
        for (int o = 1; o < 64; o <<= 1) {
            unsigned u = __shfl_up((int)s, o);
            if (lane >= o) s += u;
        }
        __syncthreads();          // wt reuse
        if (lane == 63) wt[wv] = s;
        __syncthreads();
        unsigned woff = 0;
#pragma unroll
        for (int w = 0; w < 4; w++) if (w < wv) woff += wt[w];
        unsigned excl = woff + s - cnt;
        curL[tid] = bukStartG + excl;
        int gc = b * NPB + tid;
        if (gc < n) {
            start[gc] = (int)(bukStartG + excl);
            dinv[gc] = rsqrtf(deg);
        }
    }
    __syncthreads();

    // pass2: scatter records to final CSR slots
    for (unsigned i = tid; i < mySize; i += 256) {
        unsigned long long v = buk[base + i];
        unsigned r = (unsigned)v & 0x1FFFFu;
        unsigned ci = ((unsigned)(v >> 17)) & 255u;
        float w = (float)(v >> 34) * FXI;
        unsigned pos = atomicAdd(&curL[ci], 1u);
        rec[pos] = make_int2((int)r, __float_as_int(w));
    }
}

// ---------------------------------------------------------------------------
// Kernel F: h = x @ W via MFMA 32x32x16 bf16. (unchanged)
// ---------------------------------------------------------------------------
__global__ __launch_bounds__(256) void k_gemm_mfma(const float* __restrict__ x,
                                                   const float* __restrict__ Wg,
                                                   unsigned short* __restrict__ hb, int nrows) {
    __shared__ unsigned wlds[4][8][64][4];   // 32 KB
    const int tid = threadIdx.x;

    for (int idx = tid; idx < 4 * 8 * 64; idx += 256) {
        int lane = idx & 63;
        int ks = (idx >> 6) & 7;
        int ct = idx >> 9;
        int krow = ks * 16 + 8 * (lane >> 5);
        int col = ct * 32 + (lane & 31);
        unsigned u0 = pkbf(Wg[(krow + 0) * FEAT + col], Wg[(krow + 1) * FEAT + col]);
        unsigned u1 = pkbf(Wg[(krow + 2) * FEAT + col], Wg[(krow + 3) * FEAT + col]);
        unsigned u2 = pkbf(Wg[(krow + 4) * FEAT + col], Wg[(krow + 5) * FEAT + col]);
        unsigned u3 = pkbf(Wg[(krow + 6) * FEAT + col], Wg[(krow + 7) * FEAT + col]);
        *(uint4*)&wlds[ct][ks][lane][0] = make_uint4(u0, u1, u2, u3);
    }
    __syncthreads();

    const int w = tid >> 6;
    const int lane = tid & 63;
    const int row = blockIdx.x * 128 + w * 32 + (lane & 31);
    const int rclamp = (row < nrows) ? row : 0;
    const float* xrow = x + (size_t)rclamp * FEAT + 8 * (lane >> 5);

    f32x16 acc0 = {0}, acc1 = {0}, acc2 = {0}, acc3 = {0};

#pragma unroll
    for (int ks = 0; ks < 8; ks++) {
        float4 f0 = *(const float4*)&xrow[ks * 16];
        float4 f1 = *(const float4*)&xrow[ks * 16 + 4];
        union { uint4 u; short8 s; } a;
        a.u = make_uint4(pkbf(f0.x, f0.y), pkbf(f0.z, f0.w), pkbf(f1.x, f1.y), pkbf(f1.z, f1.w));
        union { uint4 u; short8 s; } b0, b1, b2, b3;
        b0.u = *(const uint4*)&wlds[0][ks][lane][0];
        b1.u = *(const uint4*)&wlds[1][ks][lane][0];
        b2.u = *(const uint4*)&wlds[2][ks][lane][0];
        b3.u = *(const uint4*)&wlds[3][ks][lane][0];
        acc0 = __builtin_amdgcn_mfma_f32_32x32x16_bf16(a.s, b0.s, acc0, 0, 0, 0);
        acc1 = __builtin_amdgcn_mfma_f32_32x32x16_bf16(a.s, b1.s, acc1, 0, 0, 0);
        acc2 = __builtin_amdgcn_mfma_f32_32x32x16_bf16(a.s, b2.s, acc2, 0, 0, 0);
        acc3 = __builtin_amdgcn_mfma_f32_32x32x16_bf16(a.s, b3.s, acc3, 0, 0, 0);
    }

    const int rb = blockIdx.x * 128 + w * 32 + 4 * (lane >> 5);
    const int cb = lane & 31;
#pragma unroll
    for (int r = 0; r < 16; r++) {
        int rr = rb + (r & 3) + 8 * (r >> 2);
        if (rr < nrows) {
            unsigned short* p = hb + (size_t)rr * FEAT + cb;
            p[0]  = bf16of(acc0[r]);
            p[32] = bf16of(acc1[r]);
            p[64] = bf16of(acc2[r]);
            p[96] = bf16of(acc3[r]);
        }
    }
}

// ---------------------------------------------------------------------------
// Kernel G: aggregate + fused BN partials. rec=(r, ew_raw); w = ew*dinv[r]*dc.
// ---------------------------------------------------------------------------
__global__ __launch_bounds__(256) void k_agg(const int* __restrict__ start,
                                             const int2* __restrict__ rec, const float* __restrict__ dinv,
                                             const unsigned* __restrict__ hb, const float* __restrict__ b,
                                             float* __restrict__ out,
                                             float* __restrict__ ps, float* __restrict__ pss, int n) {
    const int tid = threadIdx.x;
    const int lane = tid & 63;
    const int wv = tid >> 6;
    const int j0 = lane * 2;
    const float bx = b[j0];
    const float by = b[j0 + 1];

    float sx = 0.0f, ssx = 0.0f, sy = 0.0f, ssy = 0.0f;

    for (int c = blockIdx.x * 4 + wv; c < n; c += AGG_BLOCKS * 4) {
        const int s0 = start[c];
        const int m = start[c + 1] - s0;
        const float dc = dinv[c];

        float2 hv = upbf(hb[(size_t)c * 64 + lane]);
        float ax = hv.x * dc * dc + bx;
        float ay = hv.y * dc * dc + by;

        int k = 0;
        for (; k + 7 < m; k += 8) {
            int2 r[8];
            unsigned g[8];
            float dr[8];
#pragma unroll
            for (int u = 0; u < 8; u++) r[u] = rec[s0 + k + u];
#pragma unroll
            for (int u = 0; u < 8; u++) { g[u] = hb[(size_t)r[u].x * 64 + lane]; dr[u] = dinv[r[u].x]; }
#pragma unroll
            for (int u = 0; u < 8; u++) {
                float w = __int_as_float(r[u].y) * dr[u] * dc;
                float2 v = upbf(g[u]);
                ax += v.x * w;
                ay += v.y * w;
            }
        }
        for (; k + 3 < m; k += 4) {
            int2 r[4];
            unsigned g[4];
            float dr[4];
#pragma unroll
            for (int u = 0; u < 4; u++) r[u] = rec[s0 + k + u];
#pragma unroll
            for (int u = 0; u < 4; u++) { g[u] = hb[(size_t)r[u].x * 64 + lane]; dr[u] = dinv[r[u].x]; }
#pragma unroll
            for (int u = 0; u < 4; u++) {
                float w = __int_as_float(r[u].y) * dr[u] * dc;
                float2 v = upbf(g[u]);
                ax += v.x * w;
                ay += v.y * w;
            }
        }
        for (; k < m; k++) {
            int2 r0 = rec[s0 + k];
            float w = __int_as_float(r0.y) * dinv[r0.x] * dc;
            float2 v = upbf(hb[(size_t)r0.x * 64 + lane]);
            ax += v.x * w;
            ay += v.y * w;
        }

        ax = (ax > 0.0f) ? ax : expm1f(ax);
        ay = (ay > 0.0f) ? ay : expm1f(ay);
        *(float2*)&out[(size_t)c * FEAT + j0] = make_float2(ax, ay);

        sx += ax; ssx += ax * ax;
        sy += ay; ssy += ay * ay;
    }

    __shared__ float4 sh[256];
    sh[tid] = make_float4(sx, sy, ssx, ssy);
    __syncthreads();
    if (tid < 64) {
        float4 a0 = sh[tid], a1 = sh[tid + 64], a2 = sh[tid + 128], a3 = sh[tid + 192];
        float4 t;
        t.x = a0.x + a1.x + a2.x + a3.x;
        t.y = a0.y + a1.y + a2.y + a3.y;
        t.z = a0.z + a1.z + a2.z + a3.z;
        t.w = a0.w + a1.w + a2.w + a3.w;
        *(float2*)&ps[(size_t)blockIdx.x * FEAT + 2 * tid]  = make_float2(t.x, t.y);
        *(float2*)&pss[(size_t)blockIdx.x * FEAT + 2 * tid] = make_float2(t.z, t.w);
    }
}

// ---------------------------------------------------------------------------
// Kernel H: reduce per-block BN partials -> bnsum/bnsq
// ---------------------------------------------------------------------------
__global__ __launch_bounds__(256) void k_bnreduce(const float* __restrict__ ps,
                                                  const float* __restrict__ pss,
                                                  float* __restrict__ bnsum, float* __restrict__ bnsq) {
    const int col = threadIdx.x & 127;
    const int half = threadIdx.x >> 7;
    const float* src = half ? pss : ps;
    const int rows = AGG_BLOCKS / 64;
    const int r0 = blockIdx.x * rows;
    float acc = 0.0f;
    for (int r = r0; r < r0 + rows; r++) acc += src[(size_t)r * FEAT + col];
    atomicAdd(half ? &bnsq[col] : &bnsum[col], acc);
}

// ---------------------------------------------------------------------------
// Kernel I: BN finalize — bnsum <- mu, bnsq <- rsqrt(var+eps)
// ---------------------------------------------------------------------------
__global__ void k_bn_finalize(float* __restrict__ bnsum, float* __restrict__ bnsq, float n) {
    int j = threadIdx.x;
    float mu = bnsum[j] / n;
    float var = bnsq[j] / n - mu * mu;
    if (var < 0.0f) var = 0.0f;
    bnsum[j] = mu;
    bnsq[j] = rsqrtf(var + 1e-5f);
}

// ---------------------------------------------------------------------------
// Kernel J: BN apply + LayerNorm, one wave per row, 2 cols per lane
// ---------------------------------------------------------------------------
__global__ __launch_bounds__(256) void k_bn_ln(float* __restrict__ out, const float* __restrict__ mu,
                                               const float* __restrict__ rsig,
                                               const float* __restrict__ bng, const float* __restrict__ bnb,
                                               const float* __restrict__ lng, const float* __restrict__ lnb,
                                               int n) {
    int wave = (blockIdx.x * 256 + threadIdx.x) >> 6;
    int lane = threadIdx.x & 63;
    if (wave >= n) return;
    int j0 = lane * 2;
    float2 v = *(const float2*)&out[(size_t)wave * FEAT + j0];
    float t0 = (v.x - mu[j0])     * rsig[j0]     * bng[j0]     + bnb[j0];
    float t1 = (v.y - mu[j0 + 1]) * rsig[j0 + 1] * bng[j0 + 1] + bnb[j0 + 1];
    float s = t0 + t1;
    float ss = t0 * t0 + t1 * t1;
#pragma unroll
    for (int o = 32; o; o >>= 1) {
        s  += __shfl_xor(s, o);
        ss += __shfl_xor(ss, o);
    }
    float m = s * (1.0f / FEAT);
    float var = ss * (1.0f / FEAT) - m * m;
    float r = rsqrtf(var + 1e-5f);
    float o0 = (t0 - m) * r * lng[j0]     + lnb[j0];
    float o1 = (t1 - m) * r * lng[j0 + 1] + lnb[j0 + 1];
    *(float2*)&out[(size_t)wave * FEAT + j0] = make_float2(o0, o1);
}

// ---------------------------------------------------------------------------
extern "C" void kernel_launch(void* const* d_in, const int* in_sizes, int n_in,
                              void* d_out, int out_size, void* d_ws, size_t ws_size,
                              hipStream_t stream) {
    const float* x   = (const float*)d_in[0];
    const int*   ei  = (const int*)  d_in[1];
    const float* ew  = (const float*)d_in[2];
    const float* W   = (const float*)d_in[3];
    const float* b   = (const float*)d_in[4];
    const float* bng = (const float*)d_in[5];
    const float* bnb = (const float*)d_in[6];
    const float* lng = (const float*)d_in[7];
    const float* lnb = (const float*)d_in[8];

    const int N = in_sizes[0] / FEAT;     // 50000
    const int E = in_sizes[2];            // 800000

    const int nbuk = (N + NPB - 1) / NPB;             // 196
    const int cap  = (((E / nbuk) * 5) / 4 + 127) & ~63;  // ~5184, mean+~17 sigma
    const int nblkA = (E + EPBA - 1) / EPBA;          // 196

    float* out = (float*)d_out;

    // workspace (16B-aligned segments):
    //   hb [N*64] u32 (12.8MB) | buk [nbuk*cap] u64 (~8.1MB) | rec [E] int2 (6.4MB)
    //   | dinv [N] f32 | start [N+4] i32 | gcur [256] u32 | bnsum/bnsq [128] f32
    //   | ps/pss [AGG_BLOCKS*128] f32 (2MB)
    unsigned*           hb    = (unsigned*)d_ws;
    unsigned long long* buk   = (unsigned long long*)(hb + (size_t)N * 64);
    int2*               rec   = (int2*)(buk + (size_t)nbuk * cap);
    float*              dinv  = (float*)(rec + E);
    int*                start = (int*)(dinv + N);
    unsigned*           gcur  = (unsigned*)(start + N + 4);
    float*              bnsum = (float*)(gcur + 256);
    float*              bnsq  = bnsum + FEAT;
    float*              ps    = bnsq + FEAT;
    float*              pss   = ps + (size_t)AGG_BLOCKS * FEAT;

    // A: init (cursors, BN sums, start[N]=E)
    k_init2<<<1, 256, 0, stream>>>(gcur, bnsum, bnsq, start, nbuk, cap, N, E);
    // B: bucket-partition edges (LDS histogram + reserve + scatter)
    k_bucket<<<nblkA, 256, 0, stream>>>(ei, ew, buk, gcur, E, nbuk, cap);
    // C: per-bucket CSR build (LDS atomics only)
    k_csr<<<nbuk, 256, 0, stream>>>(buk, gcur, rec, start, dinv, N, nbuk, cap);
    // F: h = x @ W (MFMA, bf16 out)
    k_gemm_mfma<<<(N + 127) / 128, 256, 0, stream>>>(x, W, (unsigned short*)hb, N);
    // G: aggregate + self-loop + bias + ELU + fused BN partials
    k_agg<<<AGG_BLOCKS, 256, 0, stream>>>(start, rec, dinv, hb, b, out, ps, pss, N);
    // H: reduce BN partials
    k_bnreduce<<<64, 256, 0, stream>>>(ps, pss, bnsum, bnsq);
    // I: BN finalize
    k_bn_finalize<<<1, FEAT, 0, stream>>>(bnsum, bnsq, (float)N);
    // J: BN apply + LayerNorm
    k_bn_ln<<<(N + 3) / 4, 256, 0, stream>>>(out, bnsum, bnsq, bng, bnb, lng, lnb, N);
}

// Round 9
// 107.312 us; speedup vs baseline: 4.7298x; 1.1507x over previous
//
#include <hip/hip_runtime.h>
#include <math.h>

#define FEAT 128
#define FXS 16777216.0f          // 2^24 fixed-point scale for edge weights
#define FXI (1.0f / 16777216.0f)
#define AGG_BLOCKS 2048          // k_agg grid; also BN partial rows
#define NPB 256                  // nodes per bucket (bucket = c >> 8)
#define EPBA 4096                // edges per phase-A block

typedef __attribute__((ext_vector_type(8)))  short short8;
typedef __attribute__((ext_vector_type(16))) float f32x16;

// bf16 helpers (bit-level, RNE pack / exact unpack)
__device__ inline unsigned pkbf(float a, float b) {
    unsigned ua = __float_as_uint(a), ub = __float_as_uint(b);
    ua += 0x7fffu + ((ua >> 16) & 1u);
    ub += 0x7fffu + ((ub >> 16) & 1u);
    return (ua >> 16) | (ub & 0xffff0000u);
}
__device__ inline unsigned short bf16of(float a) {
    unsigned ua = __float_as_uint(a);
    ua += 0x7fffu + ((ua >> 16) & 1u);
    return (unsigned short)(ua >> 16);
}
__device__ inline float2 upbf(unsigned v) {
    return make_float2(__uint_as_float(v << 16), __uint_as_float(v & 0xffff0000u));
}

// ---------------------------------------------------------------------------
// Kernel A: init — bucket cursors to region bases, BN sums=0, start[n]=E
// ---------------------------------------------------------------------------
__global__ __launch_bounds__(256) void k_init2(unsigned* __restrict__ gcur,
                                               float* __restrict__ bnsum, float* __restrict__ bnsq,
                                               int* __restrict__ start,
                                               int nbuk, int cap, int n, int E) {
    int i = threadIdx.x;
    if (i < nbuk) gcur[i] = (unsigned)(i * cap);
    if (i < FEAT) { bnsum[i] = 0.0f; bnsq[i] = 0.0f; }
    if (i == 0) start[n] = E;
}

// ---------------------------------------------------------------------------
// Kernel B (phase A): bucket-partition edges. LDS histogram over nbuk coarse
// buckets, one global atomic per (block,bucket) to reserve, LDS-cursor scatter.
// Record: u64 = r | c<<17 | fx24(ew)<<34
// ---------------------------------------------------------------------------
__global__ __launch_bounds__(256) void k_bucket(const int* __restrict__ ei, const float* __restrict__ ew,
                                                unsigned long long* __restrict__ buk,
                                                unsigned* __restrict__ gcur,
                                                int E, int nbuk, int cap) {
    __shared__ unsigned bcnt[256];
    __shared__ unsigned bbase[256];
    const int tid = threadIdx.x;
    for (int i = tid; i < nbuk; i += 256) bcnt[i] = 0;
    __syncthreads();
    const int e0 = blockIdx.x * EPBA;
    const int e1 = (e0 + EPBA < E) ? e0 + EPBA : E;
    for (int e = e0 + tid; e < e1; e += 256) {
        int c = ei[E + e];
        atomicAdd(&bcnt[c >> 8], 1u);
    }
    __syncthreads();
    for (int i = tid; i < nbuk; i += 256) {
        unsigned nn = bcnt[i];
        bbase[i] = nn ? atomicAdd(&gcur[i], nn) : 0u;
        bcnt[i] = 0;   // reuse as local cursor
    }
    __syncthreads();
    for (int e = e0 + tid; e < e1; e += 256) {
        int r = ei[e];
        int c = ei[E + e];
        unsigned fx = (unsigned)(ew[e] * FXS + 0.5f);
        int b = c >> 8;
        unsigned slot = bbase[b] + atomicAdd(&bcnt[b], 1u);
        buk[slot] = (unsigned long long)(unsigned)r
                  | ((unsigned long long)(unsigned)c << 17)
                  | ((unsigned long long)fx << 34);
    }
}

// ---------------------------------------------------------------------------
// Kernel C (phase B): per-bucket CSR build. One block per bucket.
// ---------------------------------------------------------------------------
__global__ __launch_bounds__(256) void k_csr(const unsigned long long* __restrict__ buk,
                                             const unsigned* __restrict__ gcur,
                                             int2* __restrict__ rec, int* __restrict__ start,
                                             float* __restrict__ dinv,
                                             int n, int nbuk, int cap) {
    __shared__ unsigned long long cd[NPB];
    __shared__ unsigned curL[NPB];
    __shared__ unsigned sizeL[256];
    __shared__ unsigned wt[4];
    const int b = blockIdx.x;
    const int tid = threadIdx.x;
    const int lane = tid & 63;
    const int wv = tid >> 6;

    unsigned sz = (tid < nbuk) ? (gcur[tid] - (unsigned)(tid * cap)) : 0u;
    {
        unsigned s = sz;
#pragma unroll
        for (int o = 1; o < 64; o <<= 1) {
            unsigned u = __shfl_up((int)s, o);
            if (lane >= o) s += u;
        }
        if (lane == 63) wt[wv] = s;
        __syncthreads();
        unsigned woff = 0;
#pragma unroll
        for (int w = 0; w < 4; w++) if (w < wv) woff += wt[w];
        sizeL[tid] = woff + s - sz;   // exclusive
        __syncthreads();
    }
    const unsigned bukStartG = sizeL[b];
    const unsigned mySize = gcur[b] - (unsigned)(b * cap);
    const unsigned base = (unsigned)b * (unsigned)cap;

    cd[tid] = 0ULL;
    __syncthreads();

    for (unsigned i = tid; i < mySize; i += 256) {
        unsigned long long v = buk[base + i];
        unsigned ci = ((unsigned)(v >> 17)) & 255u;
        atomicAdd(&cd[ci], (1ULL << 40) | (v >> 34));
    }
    __syncthreads();

    {
        unsigned long long v = cd[tid];
        unsigned cnt = (unsigned)(v >> 40);
        float deg = 1.0f + (float)(v & ((1ULL << 40) - 1ULL)) * FXI;
        unsigned s = cnt;
#pragma unroll
        for (int o = 1; o < 64; o <<= 1) {
            unsigned u = __shfl_up((int)s, o);
            if (lane >= o) s += u;
        }
        __syncthreads();          // wt reuse
        if (lane == 63) wt[wv] = s;
        __syncthreads();
        unsigned woff = 0;
#pragma unroll
        for (int w = 0; w < 4; w++) if (w < wv) woff += wt[w];
        unsigned excl = woff + s - cnt;
        curL[tid] = bukStartG + excl;
        int gc = b * NPB + tid;
        if (gc < n) {
            start[gc] = (int)(bukStartG + excl);
            dinv[gc] = rsqrtf(deg);
        }
    }
    __syncthreads();

    for (unsigned i = tid; i < mySize; i += 256) {
        unsigned long long v = buk[base + i];
        unsigned r = (unsigned)v & 0x1FFFFu;
        unsigned ci = ((unsigned)(v >> 17)) & 255u;
        float w = (float)(v >> 34) * FXI;
        unsigned pos = atomicAdd(&curL[ci], 1u);
        rec[pos] = make_int2((int)r, __float_as_int(w));
    }
}

// ---------------------------------------------------------------------------
// Kernel F: hbs = (x @ W) * dinv[row]  via MFMA 32x32x16 bf16 (dinv pre-scaled)
// ---------------------------------------------------------------------------
__global__ __launch_bounds__(256) void k_gemm_mfma(const float* __restrict__ x,
                                                   const float* __restrict__ Wg,
                                                   const float* __restrict__ dinv,
                                                   unsigned short* __restrict__ hb, int nrows) {
    __shared__ unsigned wlds[4][8][64][4];   // 32 KB
    const int tid = threadIdx.x;

    for (int idx = tid; idx < 4 * 8 * 64; idx += 256) {
        int lane = idx & 63;
        int ks = (idx >> 6) & 7;
        int ct = idx >> 9;
        int krow = ks * 16 + 8 * (lane >> 5);
        int col = ct * 32 + (lane & 31);
        unsigned u0 = pkbf(Wg[(krow + 0) * FEAT + col], Wg[(krow + 1) * FEAT + col]);
        unsigned u1 = pkbf(Wg[(krow + 2) * FEAT + col], Wg[(krow + 3) * FEAT + col]);
        unsigned u2 = pkbf(Wg[(krow + 4) * FEAT + col], Wg[(krow + 5) * FEAT + col]);
        unsigned u3 = pkbf(Wg[(krow + 6) * FEAT + col], Wg[(krow + 7) * FEAT + col]);
        *(uint4*)&wlds[ct][ks][lane][0] = make_uint4(u0, u1, u2, u3);
    }
    __syncthreads();

    const int w = tid >> 6;
    const int lane = tid & 63;
    const int row = blockIdx.x * 128 + w * 32 + (lane & 31);
    const int rclamp = (row < nrows) ? row : 0;
    const float* xrow = x + (size_t)rclamp * FEAT + 8 * (lane >> 5);

    f32x16 acc0 = {0}, acc1 = {0}, acc2 = {0}, acc3 = {0};

#pragma unroll
    for (int ks = 0; ks < 8; ks++) {
        float4 f0 = *(const float4*)&xrow[ks * 16];
        float4 f1 = *(const float4*)&xrow[ks * 16 + 4];
        union { uint4 u; short8 s; } a;
        a.u = make_uint4(pkbf(f0.x, f0.y), pkbf(f0.z, f0.w), pkbf(f1.x, f1.y), pkbf(f1.z, f1.w));
        union { uint4 u; short8 s; } b0, b1, b2, b3;
        b0.u = *(const uint4*)&wlds[0][ks][lane][0];
        b1.u = *(const uint4*)&wlds[1][ks][lane][0];
        b2.u = *(const uint4*)&wlds[2][ks][lane][0];
        b3.u = *(const uint4*)&wlds[3][ks][lane][0];
        acc0 = __builtin_amdgcn_mfma_f32_32x32x16_bf16(a.s, b0.s, acc0, 0, 0, 0);
        acc1 = __builtin_amdgcn_mfma_f32_32x32x16_bf16(a.s, b1.s, acc1, 0, 0, 0);
        acc2 = __builtin_amdgcn_mfma_f32_32x32x16_bf16(a.s, b2.s, acc2, 0, 0, 0);
        acc3 = __builtin_amdgcn_mfma_f32_32x32x16_bf16(a.s, b3.s, acc3, 0, 0, 0);
    }

    const int rb = blockIdx.x * 128 + w * 32 + 4 * (lane >> 5);
    const int cb = lane & 31;
#pragma unroll
    for (int r = 0; r < 16; r++) {
        int rr = rb + (r & 3) + 8 * (r >> 2);
        if (rr < nrows) {
            float dv = dinv[rr];
            unsigned short* p = hb + (size_t)rr * FEAT + cb;
            p[0]  = bf16of(acc0[r] * dv);
            p[32] = bf16of(acc1[r] * dv);
            p[64] = bf16of(acc2[r] * dv);
            p[96] = bf16of(acc3[r] * dv);
        }
    }
}

// ---------------------------------------------------------------------------
// Kernel G: aggregate + fused BN partials. hbs = h*dinv (pre-scaled).
// out[c] = ELU( sum hbs[r]*(ew*dc) + hbs[c]*dc + b ), stored bf16x2 in obf.
// ---------------------------------------------------------------------------
__global__ __launch_bounds__(256) void k_agg(const int* __restrict__ start,
                                             const int2* __restrict__ rec, const float* __restrict__ dinv,
                                             const unsigned* __restrict__ hb, const float* __restrict__ b,
                                             unsigned* __restrict__ obf,
                                             float* __restrict__ ps, float* __restrict__ pss, int n) {
    const int tid = threadIdx.x;
    const int lane = tid & 63;
    const int wv = tid >> 6;
    const int j0 = lane * 2;
    const float bx = b[j0];
    const float by = b[j0 + 1];

    float sx = 0.0f, ssx = 0.0f, sy = 0.0f, ssy = 0.0f;

    for (int c = blockIdx.x * 4 + wv; c < n; c += AGG_BLOCKS * 4) {
        const int s0 = start[c];
        const int m = start[c + 1] - s0;
        const float dc = dinv[c];

        float2 hv = upbf(hb[(size_t)c * 64 + lane]);
        float ax = hv.x * dc + bx;
        float ay = hv.y * dc + by;

        int k = 0;
        for (; k + 7 < m; k += 8) {
            int2 r[8];
            unsigned g[8];
#pragma unroll
            for (int u = 0; u < 8; u++) r[u] = rec[s0 + k + u];
#pragma unroll
            for (int u = 0; u < 8; u++) g[u] = hb[(size_t)r[u].x * 64 + lane];
#pragma unroll
            for (int u = 0; u < 8; u++) {
                float w = __int_as_float(r[u].y) * dc;
                float2 v = upbf(g[u]);
                ax += v.x * w;
                ay += v.y * w;
            }
        }
        for (; k + 3 < m; k += 4) {
            int2 r[4];
            unsigned g[4];
#pragma unroll
            for (int u = 0; u < 4; u++) r[u] = rec[s0 + k + u];
#pragma unroll
            for (int u = 0; u < 4; u++) g[u] = hb[(size_t)r[u].x * 64 + lane];
#pragma unroll
            for (int u = 0; u < 4; u++) {
                float w = __int_as_float(r[u].y) * dc;
                float2 v = upbf(g[u]);
                ax += v.x * w;
                ay += v.y * w;
            }
        }
        for (; k < m; k++) {
            int2 r0 = rec[s0 + k];
            float w = __int_as_float(r0.y) * dc;
            float2 v = upbf(hb[(size_t)r0.x * 64 + lane]);
            ax += v.x * w;
            ay += v.y * w;
        }

        ax = (ax > 0.0f) ? ax : expm1f(ax);
        ay = (ay > 0.0f) ? ay : expm1f(ay);
        obf[(size_t)c * 64 + lane] = pkbf(ax, ay);

        sx += ax; ssx += ax * ax;
        sy += ay; ssy += ay * ay;
    }

    __shared__ float4 sh[256];
    sh[tid] = make_float4(sx, sy, ssx, ssy);
    __syncthreads();
    if (tid < 64) {
        float4 a0 = sh[tid], a1 = sh[tid + 64], a2 = sh[tid + 128], a3 = sh[tid + 192];
        float4 t;
        t.x = a0.x + a1.x + a2.x + a3.x;
        t.y = a0.y + a1.y + a2.y + a3.y;
        t.z = a0.z + a1.z + a2.z + a3.z;
        t.w = a0.w + a1.w + a2.w + a3.w;
        *(float2*)&ps[(size_t)blockIdx.x * FEAT + 2 * tid]  = make_float2(t.x, t.y);
        *(float2*)&pss[(size_t)blockIdx.x * FEAT + 2 * tid] = make_float2(t.z, t.w);
    }
}

// ---------------------------------------------------------------------------
// Kernel H: reduce per-block BN partials -> bnsum/bnsq
// ---------------------------------------------------------------------------
__global__ __launch_bounds__(256) void k_bnreduce(const float* __restrict__ ps,
                                                  const float* __restrict__ pss,
                                                  float* __restrict__ bnsum, float* __restrict__ bnsq) {
    const int col = threadIdx.x & 127;
    const int half = threadIdx.x >> 7;
    const float* src = half ? pss : ps;
    const int rows = AGG_BLOCKS / 64;
    const int r0 = blockIdx.x * rows;
    float acc = 0.0f;
    for (int r = r0; r < r0 + rows; r++) acc += src[(size_t)r * FEAT + col];
    atomicAdd(half ? &bnsq[col] : &bnsum[col], acc);
}

// ---------------------------------------------------------------------------
// Kernel I: BN finalize — bnsum <- mu, bnsq <- rsqrt(var+eps)
// ---------------------------------------------------------------------------
__global__ void k_bn_finalize(float* __restrict__ bnsum, float* __restrict__ bnsq, float n) {
    int j = threadIdx.x;
    float mu = bnsum[j] / n;
    float var = bnsq[j] / n - mu * mu;
    if (var < 0.0f) var = 0.0f;
    bnsum[j] = mu;
    bnsq[j] = rsqrtf(var + 1e-5f);
}

// ---------------------------------------------------------------------------
// Kernel J: BN apply + LayerNorm; reads bf16x2 obf, writes fp32 out.
// ---------------------------------------------------------------------------
__global__ __launch_bounds__(256) void k_bn_ln(const unsigned* __restrict__ obf,
                                               float* __restrict__ out, const float* __restrict__ mu,
                                               const float* __restrict__ rsig,
                                               const float* __restrict__ bng, const float* __restrict__ bnb,
                                               const float* __restrict__ lng, const float* __restrict__ lnb,
                                               int n) {
    int wave = (blockIdx.x * 256 + threadIdx.x) >> 6;
    int lane = threadIdx.x & 63;
    if (wave >= n) return;
    int j0 = lane * 2;
    float2 v = upbf(obf[(size_t)wave * 64 + lane]);
    float t0 = (v.x - mu[j0])     * rsig[j0]     * bng[j0]     + bnb[j0];
    float t1 = (v.y - mu[j0 + 1]) * rsig[j0 + 1] * bng[j0 + 1] + bnb[j0 + 1];
    float s = t0 + t1;
    float ss = t0 * t0 + t1 * t1;
#pragma unroll
    for (int o = 32; o; o >>= 1) {
        s  += __shfl_xor(s, o);
        ss += __shfl_xor(ss, o);
    }
    float m = s * (1.0f / FEAT);
    float var = ss * (1.0f / FEAT) - m * m;
    float r = rsqrtf(var + 1e-5f);
    float o0 = (t0 - m) * r * lng[j0]     + lnb[j0];
    float o1 = (t1 - m) * r * lng[j0 + 1] + lnb[j0 + 1];
    *(float2*)&out[(size_t)wave * FEAT + j0] = make_float2(o0, o1);
}

// ---------------------------------------------------------------------------
extern "C" void kernel_launch(void* const* d_in, const int* in_sizes, int n_in,
                              void* d_out, int out_size, void* d_ws, size_t ws_size,
                              hipStream_t stream) {
    const float* x   = (const float*)d_in[0];
    const int*   ei  = (const int*)  d_in[1];
    const float* ew  = (const float*)d_in[2];
    const float* W   = (const float*)d_in[3];
    const float* b   = (const float*)d_in[4];
    const float* bng = (const float*)d_in[5];
    const float* bnb = (const float*)d_in[6];
    const float* lng = (const float*)d_in[7];
    const float* lnb = (const float*)d_in[8];

    const int N = in_sizes[0] / FEAT;     // 50000
    const int E = in_sizes[2];            // 800000

    const int nbuk = (N + NPB - 1) / NPB;                 // 196
    const int cap  = (((E / nbuk) * 5) / 4 + 127) & ~63;  // ~5184
    const int nblkA = (E + EPBA - 1) / EPBA;              // 196

    float* out = (float*)d_out;

    // workspace (16B-aligned; hb overlays buk — disjoint lifetimes:
    //   buk live [k_bucket..k_csr], hb written first by k_gemm_mfma after k_csr)
    unsigned*           hb    = (unsigned*)d_ws;                       // N*64 u32 = 12.8MB
    unsigned long long* buk   = (unsigned long long*)d_ws;             // nbuk*cap u64 ~ 8.1MB (overlay)
    size_t hbWords = (size_t)N * 64;
    size_t bukWords2 = ((size_t)nbuk * cap * 2);                       // u64 -> 2 u32 words
    size_t reg1 = hbWords > bukWords2 ? hbWords : bukWords2;
    int2*               rec   = (int2*)(hb + reg1);                    // E int2 = 6.4MB
    unsigned*           obf   = (unsigned*)(rec + E);                  // N*64 u32 = 12.8MB
    float*              dinv  = (float*)(obf + (size_t)N * 64);        // N f32
    int*                start = (int*)(dinv + N);                      // N+4 i32
    unsigned*           gcur  = (unsigned*)(start + N + 4);            // 256 u32
    float*              bnsum = (float*)(gcur + 256);
    float*              bnsq  = bnsum + FEAT;
    float*              ps    = bnsq + FEAT;                           // AGG_BLOCKS*128
    float*              pss   = ps + (size_t)AGG_BLOCKS * FEAT;        // AGG_BLOCKS*128

    // A: init (cursors, BN sums, start[N]=E)
    k_init2<<<1, 256, 0, stream>>>(gcur, bnsum, bnsq, start, nbuk, cap, N, E);
    // B: bucket-partition edges
    k_bucket<<<nblkA, 256, 0, stream>>>(ei, ew, buk, gcur, E, nbuk, cap);
    // C: per-bucket CSR build (writes dinv)
    k_csr<<<nbuk, 256, 0, stream>>>(buk, gcur, rec, start, dinv, N, nbuk, cap);
    // F: hbs = (x @ W)*dinv (MFMA, bf16 out) — overlays buk, after csr
    k_gemm_mfma<<<(N + 127) / 128, 256, 0, stream>>>(x, W, dinv, (unsigned short*)hb, N);
    // G: aggregate + self-loop + bias + ELU + fused BN partials -> obf (bf16)
    k_agg<<<AGG_BLOCKS, 256, 0, stream>>>(start, rec, dinv, hb, b, obf, ps, pss, N);
    // H: reduce BN partials
    k_bnreduce<<<64, 256, 0, stream>>>(ps, pss, bnsum, bnsq);
    // I: BN finalize
    k_bn_finalize<<<1, FEAT, 0, stream>>>(bnsum, bnsq, (float)N);
    // J: BN apply + LayerNorm (obf -> fp32 out)
    k_bn_ln<<<(N + 3) / 4, 256, 0, stream>>>(obf, out, bnsum, bnsq, bng, bnb, lng, lnb, N);
}